// Round 1
// baseline (303.825 us; speedup 1.0000x reference)
//
#include <hip/hip_runtime.h>
#include <hip/hip_bf16.h>

typedef __attribute__((ext_vector_type(4))) float f32x4;
typedef __attribute__((ext_vector_type(8))) short bf16x8;
typedef unsigned short u16;

#define T_SEQ 2048
#define DMODEL 1024

__device__ __forceinline__ u16 f2bf(float f) {
    __hip_bfloat16 h = __float2bfloat16(f);
    return __builtin_bit_cast(unsigned short, h);
}

typedef const void __attribute__((address_space(1))) gvoid_t;
typedef void __attribute__((address_space(3))) lvoid_t;
__device__ __forceinline__ void gload16(const void* g, void* l) {
    __builtin_amdgcn_global_load_lds((gvoid_t*)g, (lvoid_t*)l, 16, 0, 0);
}

// ---------------- cast f32 -> bf16 (vectorized x4) ----------------
__global__ __launch_bounds__(256) void cast_bf16(const float* __restrict__ s,
                                                 u16* __restrict__ d, int n) {
    int i = (blockIdx.x * 256 + threadIdx.x) * 4;
    if (i >= n) return;
    float4 v = *(const float4*)(s + i);
    ushort4 o;
    o.x = f2bf(v.x); o.y = f2bf(v.y); o.z = f2bf(v.z); o.w = f2bf(v.w);
    *(ushort4*)(d + i) = o;
}

// ---------------- rope tables ----------------
__global__ __launch_bounds__(256) void rope_tables(float* __restrict__ cosT,
                                                   float* __restrict__ sinT) {
    int i = blockIdx.x * 256 + threadIdx.x;   // < 2048*32
    int t = i >> 5, j = i & 31;
    float inv = powf(10000.0f, -(float)j * (1.0f / 32.0f));
    float fr = (float)t * inv;
    cosT[i] = cosf(fr);
    sinT[i] = sinf(fr);
}

// ---------------- lambda scalar ----------------
__global__ void lambda_kernel(const float* lq1, const float* lk1,
                              const float* lq2, const float* lk2, float* lam) {
    if (threadIdx.x == 0) {
        float s1 = 0.f, s2 = 0.f;
        for (int i = 0; i < 32; ++i) { s1 += lq1[i] * lk1[i]; s2 += lq2[i] * lk2[i]; }
        *lam = expf(s1) - expf(s2) + 0.35550906759096928f;
    }
}

// ---------------- GEMM: C[M,N] = A[M,K](bf16) * B[N,K]^T(bf16), f32 out ----------
// 128x128 tile, BK=32, 4 waves, 16x16x32 bf16 MFMA, global_load_lds width 16.
__global__ __launch_bounds__(256) void gemm_bt_f32(const u16* __restrict__ A,
                                                   const u16* __restrict__ B,
                                                   float* __restrict__ C,
                                                   int M, int N, int K) {
    __shared__ __align__(16) u16 lA[128 * 32];
    __shared__ __align__(16) u16 lB[128 * 32];
    const int tid = threadIdx.x;
    const int lane = tid & 63;
    const int wid = tid >> 6;
    const int m0 = blockIdx.y * 128;
    const int n0 = blockIdx.x * 128;
    const int wr = (wid >> 1) * 64;
    const int wc = (wid & 1) * 64;
    const int fr = lane & 15;
    const int kc = lane >> 4;

    f32x4 acc[4][4] = {};
    const char* Ab = (const char*)A;
    const char* Bb = (const char*)B;
    const int rowbytes = K * 2;

    for (int k0 = 0; k0 < K; k0 += 32) {
#pragma unroll
        for (int i = 0; i < 2; ++i) {
            int c = i * 256 + tid;
            gload16(Ab + (size_t)(m0 + (c >> 2)) * rowbytes + k0 * 2 + (c & 3) * 16,
                    (char*)lA + c * 16);
            gload16(Bb + (size_t)(n0 + (c >> 2)) * rowbytes + k0 * 2 + (c & 3) * 16,
                    (char*)lB + c * 16);
        }
        __syncthreads();
        bf16x8 a[4], b[4];
#pragma unroll
        for (int m = 0; m < 4; ++m) a[m] = *(const bf16x8*)&lA[(wr + m * 16 + fr) * 32 + kc * 8];
#pragma unroll
        for (int n = 0; n < 4; ++n) b[n] = *(const bf16x8*)&lB[(wc + n * 16 + fr) * 32 + kc * 8];
#pragma unroll
        for (int m = 0; m < 4; ++m)
#pragma unroll
            for (int n = 0; n < 4; ++n)
                acc[m][n] = __builtin_amdgcn_mfma_f32_16x16x32_bf16(a[m], b[n], acc[m][n], 0, 0, 0);
        __syncthreads();
    }

    const int rr = (lane >> 4) * 4;
#pragma unroll
    for (int m = 0; m < 4; ++m)
#pragma unroll
        for (int n = 0; n < 4; ++n)
#pragma unroll
            for (int r = 0; r < 4; ++r)
                C[(size_t)(m0 + wr + m * 16 + rr + r) * N + (n0 + wc + n * 16 + fr)] = acc[m][n][r];
}

// ---------------- fused RMS-norm + RoPE, pack to bf16 planes ----------------
// rows: [tensor(2)][t(2048)][p(2)][h(8)], one wave (64 lanes = 64 dims) per row
__global__ __launch_bounds__(256) void norm_rope(const float* __restrict__ Qf,
                                                 const float* __restrict__ Kf,
                                                 const float* __restrict__ cosT,
                                                 const float* __restrict__ sinT,
                                                 u16* __restrict__ q_bf,
                                                 u16* __restrict__ k_bf) {
    int row = blockIdx.x * 4 + (threadIdx.x >> 6);
    int lane = threadIdx.x & 63;
    int tensor = row >> 15;
    int r = row & 32767;
    int t = r >> 4, p = (r >> 3) & 1, h = r & 7;
    const float* src = (tensor ? Kf : Qf) + (size_t)t * 1024 + p * 512 + h * 64 + lane;
    float x = *src;
    float ss = x * x;
    ss += __shfl_xor(ss, 1);  ss += __shfl_xor(ss, 2);  ss += __shfl_xor(ss, 4);
    ss += __shfl_xor(ss, 8);  ss += __shfl_xor(ss, 16); ss += __shfl_xor(ss, 32);
    float xn = x * rsqrtf(ss * (1.0f / 64.0f) + 1.1920929e-7f);
    float other = __shfl_xor(xn, 32);
    int j = lane & 31;
    float c = cosT[t * 32 + j], s = sinT[t * 32 + j];
    float out = (lane < 32) ? (xn * c + other * s) : (xn * c - other * s);
    u16* dst = (tensor ? k_bf : q_bf) + ((size_t)(p * 8 + h) * T_SEQ + t) * 64 + lane;
    *dst = f2bf(out);
}

// ---------------- V transpose: Vf[t][1024] f32 -> vT[h*128+d][t] bf16 ----------
__global__ __launch_bounds__(256) void vtrans(const float* __restrict__ Vf,
                                              u16* __restrict__ vT) {
    __shared__ float tile[32][33];
    int tx = threadIdx.x & 31;
    int ty = threadIdx.x >> 5;
    int c0 = blockIdx.x * 32;   // column of Vf (0..1023)
    int r0 = blockIdx.y * 32;   // row t
#pragma unroll
    for (int i = ty; i < 32; i += 8)
        tile[i][tx] = Vf[(size_t)(r0 + i) * 1024 + c0 + tx];
    __syncthreads();
#pragma unroll
    for (int i = ty; i < 32; i += 8)
        vT[(size_t)(c0 + i) * T_SEQ + r0 + tx] = f2bf(tile[tx][i]);
}

// ---------------- flash attention (causal), diff-attn variant in z ------------
// block: 4 waves x 32 q-rows = 128 q-rows. KV tile = 64.
__global__ __launch_bounds__(256) void attn_kernel(const u16* __restrict__ q_bf,
                                                   const u16* __restrict__ k_bf,
                                                   const u16* __restrict__ vT_bf,
                                                   float* __restrict__ y_out) {
    __shared__ __align__(16) u16 lK[64 * 64];
    __shared__ __align__(16) u16 lV[128 * 64];
    __shared__ __align__(16) u16 lP[4][32 * 64];

    const int tid = threadIdx.x, lane = tid & 63, wid = tid >> 6;
    const int qt = blockIdx.x, h = blockIdx.y, v = blockIdx.z;
    const int q0 = qt * 128;
    const int plane = v * 8 + h;
    const u16* qp = q_bf + (size_t)plane * T_SEQ * 64;
    const char* kp = (const char*)(k_bf + (size_t)plane * T_SEQ * 64);
    const char* vp = (const char*)(vT_bf + (size_t)h * 128 * T_SEQ);
    const int fr = lane & 15, kc = lane >> 4;
    const int wsub = wid * 32;

    bf16x8 aq[2][2];
#pragma unroll
    for (int m = 0; m < 2; ++m)
#pragma unroll
        for (int kq = 0; kq < 2; ++kq)
            aq[m][kq] = *(const bf16x8*)(qp + (size_t)(q0 + wsub + m * 16 + fr) * 64 + kq * 32 + kc * 8);

    f32x4 o[2][8] = {};
    float mi[2][4], li[2][4];
#pragma unroll
    for (int m = 0; m < 2; ++m)
#pragma unroll
        for (int r = 0; r < 4; ++r) { mi[m][r] = -INFINITY; li[m][r] = 0.f; }

    const int qmax_wave = q0 + wsub + 31;
    const float scale = 0.125f;

    for (int s0 = 0; s0 < q0 + 128; s0 += 64) {
        // stage K(64x64) and Vt(128x64)
#pragma unroll
        for (int i = 0; i < 2; ++i) {
            int c = i * 256 + tid;
            gload16(kp + (size_t)(s0 + (c >> 3)) * 128 + (c & 7) * 16, (char*)lK + c * 16);
        }
#pragma unroll
        for (int i = 0; i < 4; ++i) {
            int c = i * 256 + tid;
            gload16(vp + (size_t)(c >> 3) * (T_SEQ * 2) + (size_t)s0 * 2 + (c & 7) * 16,
                    (char*)lV + c * 16);
        }
        __syncthreads();

        if (s0 <= qmax_wave) {
            f32x4 sacc[2][4] = {};
            bf16x8 bk[4][2];
#pragma unroll
            for (int n = 0; n < 4; ++n)
#pragma unroll
                for (int kq = 0; kq < 2; ++kq)
                    bk[n][kq] = *(const bf16x8*)&lK[(n * 16 + fr) * 64 + kq * 32 + kc * 8];
#pragma unroll
            for (int m = 0; m < 2; ++m)
#pragma unroll
                for (int n = 0; n < 4; ++n)
#pragma unroll
                    for (int kq = 0; kq < 2; ++kq)
                        sacc[m][n] = __builtin_amdgcn_mfma_f32_16x16x32_bf16(aq[m][kq], bk[n][kq], sacc[m][n], 0, 0, 0);

            // mask + scale + online softmax (rows: m*16 + (lane>>4)*4 + r)
#pragma unroll
            for (int m = 0; m < 2; ++m) {
                const int qrow = q0 + wsub + m * 16 + (lane >> 4) * 4;
#pragma unroll
                for (int r = 0; r < 4; ++r) {
                    float rmax = -INFINITY;
#pragma unroll
                    for (int n = 0; n < 4; ++n) {
                        float sv = sacc[m][n][r] * scale;
                        if (s0 + n * 16 + fr > qrow + r) sv = -INFINITY;
                        sacc[m][n][r] = sv;
                        rmax = fmaxf(rmax, sv);
                    }
                    rmax = fmaxf(rmax, __shfl_xor(rmax, 1));
                    rmax = fmaxf(rmax, __shfl_xor(rmax, 2));
                    rmax = fmaxf(rmax, __shfl_xor(rmax, 4));
                    rmax = fmaxf(rmax, __shfl_xor(rmax, 8));
                    float mo = mi[m][r];
                    float mn = fmaxf(mo, rmax);
                    float f = expf(mo - mn);
                    mi[m][r] = mn;
                    float rs = 0.f;
#pragma unroll
                    for (int n = 0; n < 4; ++n) {
                        float p = expf(sacc[m][n][r] - mn);
                        sacc[m][n][r] = p;
                        rs += p;
                    }
                    rs += __shfl_xor(rs, 1); rs += __shfl_xor(rs, 2);
                    rs += __shfl_xor(rs, 4); rs += __shfl_xor(rs, 8);
                    li[m][r] = li[m][r] * f + rs;
#pragma unroll
                    for (int n8 = 0; n8 < 8; ++n8) o[m][n8][r] *= f;
                }
            }
            // P -> LDS (bf16), per-wave region
#pragma unroll
            for (int m = 0; m < 2; ++m)
#pragma unroll
                for (int n = 0; n < 4; ++n)
#pragma unroll
                    for (int r = 0; r < 4; ++r)
                        lP[wid][(m * 16 + (lane >> 4) * 4 + r) * 64 + n * 16 + fr] = f2bf(sacc[m][n][r]);
            // PV: O += P(32x64) * V(64x128)
#pragma unroll
            for (int kk = 0; kk < 2; ++kk) {
                bf16x8 ap[2];
#pragma unroll
                for (int m = 0; m < 2; ++m)
                    ap[m] = *(const bf16x8*)&lP[wid][(m * 16 + fr) * 64 + kk * 32 + kc * 8];
#pragma unroll
                for (int n8 = 0; n8 < 8; ++n8) {
                    bf16x8 bv = *(const bf16x8*)&lV[(n8 * 16 + fr) * 64 + kk * 32 + kc * 8];
#pragma unroll
                    for (int m = 0; m < 2; ++m)
                        o[m][n8] = __builtin_amdgcn_mfma_f32_16x16x32_bf16(ap[m], bv, o[m][n8], 0, 0, 0);
                }
            }
        }
        __syncthreads();
    }

    // epilogue: y_out[v][t][h*128 + d]
#pragma unroll
    for (int m = 0; m < 2; ++m)
#pragma unroll
        for (int r = 0; r < 4; ++r) {
            int t = q0 + wsub + m * 16 + (lane >> 4) * 4 + r;
            float inv_l = 1.0f / li[m][r];
#pragma unroll
            for (int n8 = 0; n8 < 8; ++n8)
                y_out[(size_t)v * T_SEQ * DMODEL + (size_t)t * DMODEL + h * 128 + n8 * 16 + fr] =
                    o[m][n8][r] * inv_l;
        }
}

// ---------------- combine y1 - lambda*y2 -> bf16 ----------------
__global__ __launch_bounds__(256) void combine(const float* __restrict__ y,
                                               const float* __restrict__ lamp,
                                               u16* __restrict__ yc) {
    int i = (blockIdx.x * 256 + threadIdx.x) * 4;
    float l = *lamp;
    float4 a = *(const float4*)(y + i);
    float4 b = *(const float4*)(y + 2097152 + i);
    ushort4 o;
    o.x = f2bf(a.x - l * b.x);
    o.y = f2bf(a.y - l * b.y);
    o.z = f2bf(a.z - l * b.z);
    o.w = f2bf(a.w - l * b.w);
    *(ushort4*)(yc + i) = o;
}

extern "C" void kernel_launch(void* const* d_in, const int* in_sizes, int n_in,
                              void* d_out, int out_size, void* d_ws, size_t ws_size,
                              hipStream_t stream) {
    const float* x   = (const float*)d_in[0];
    const float* Wq  = (const float*)d_in[1];
    const float* Wk  = (const float*)d_in[2];
    const float* Wv  = (const float*)d_in[3];
    const float* Wp  = (const float*)d_in[4];
    const float* lq1 = (const float*)d_in[5];
    const float* lk1 = (const float*)d_in[6];
    const float* lq2 = (const float*)d_in[7];
    const float* lk2 = (const float*)d_in[8];
    float* out = (float*)d_out;

    char* ws = (char*)d_ws;
    u16*   x_bf  = (u16*)(ws);                         //  4 MB
    u16*   wq_bf = (u16*)(ws + (4ull << 20));          //  2 MB
    u16*   wk_bf = (u16*)(ws + (6ull << 20));
    u16*   wv_bf = (u16*)(ws + (8ull << 20));
    u16*   wp_bf = (u16*)(ws + (10ull << 20));
    float* Qf    = (float*)(ws + (12ull << 20));       //  8 MB
    float* Kf    = (float*)(ws + (20ull << 20));       //  8 MB
    float* Vf    = (float*)(ws + (28ull << 20));       //  8 MB
    u16*   q_bf  = (u16*)(ws + (36ull << 20));         //  4 MB
    u16*   k_bf  = (u16*)(ws + (40ull << 20));         //  4 MB
    u16*   vT_bf = (u16*)(ws + (44ull << 20));         //  4 MB
    float* y12   = (float*)(ws + (48ull << 20));       // 16 MB
    u16*   yc_bf = (u16*)(ws + (64ull << 20));         //  4 MB
    float* cosT  = (float*)(ws + (68ull << 20));
    float* sinT  = (float*)(ws + (68ull << 20) + (256ull << 10));
    float* lam   = (float*)(ws + (68ull << 20) + (512ull << 10));

    cast_bf16<<<2048, 256, 0, stream>>>(x,  x_bf,  2048 * 1024);
    cast_bf16<<<1024, 256, 0, stream>>>(Wq, wq_bf, 1024 * 1024);
    cast_bf16<<<1024, 256, 0, stream>>>(Wk, wk_bf, 1024 * 1024);
    cast_bf16<<<1024, 256, 0, stream>>>(Wv, wv_bf, 1024 * 1024);
    cast_bf16<<<1024, 256, 0, stream>>>(Wp, wp_bf, 1024 * 1024);
    rope_tables<<<256, 256, 0, stream>>>(cosT, sinT);
    lambda_kernel<<<1, 64, 0, stream>>>(lq1, lk1, lq2, lk2, lam);

    dim3 g(8, 16);
    gemm_bt_f32<<<g, 256, 0, stream>>>(x_bf, wq_bf, Qf, 2048, 1024, 1024);
    gemm_bt_f32<<<g, 256, 0, stream>>>(x_bf, wk_bf, Kf, 2048, 1024, 1024);
    gemm_bt_f32<<<g, 256, 0, stream>>>(x_bf, wv_bf, Vf, 2048, 1024, 1024);

    norm_rope<<<16384, 256, 0, stream>>>(Qf, Kf, cosT, sinT, q_bf, k_bf);
    vtrans<<<dim3(32, 64), 256, 0, stream>>>(Vf, vT_bf);

    attn_kernel<<<dim3(16, 8, 2), 256, 0, stream>>>(q_bf, k_bf, vT_bf, y12);

    combine<<<2048, 256, 0, stream>>>(y12, lam, yc_bf);
    gemm_bt_f32<<<g, 256, 0, stream>>>(yc_bf, wp_bf, out, 2048, 1024, 1024);
}

// Round 2
// 163.747 us; speedup vs baseline: 1.8555x; 1.8555x over previous
//
#include <hip/hip_runtime.h>
#include <hip/hip_bf16.h>

typedef __attribute__((ext_vector_type(4))) float f32x4;
typedef __attribute__((ext_vector_type(8))) short bf16x8;
typedef unsigned short u16;

#define T_SEQ 2048
#define DMODEL 1024

__device__ __forceinline__ u16 f2bf(float f) {
    __hip_bfloat16 h = __float2bfloat16(f);
    return __builtin_bit_cast(unsigned short, h);
}

typedef const void __attribute__((address_space(1))) gvoid_t;
typedef void __attribute__((address_space(3))) lvoid_t;
__device__ __forceinline__ void gload16(const void* g, void* l) {
    __builtin_amdgcn_global_load_lds((gvoid_t*)g, (lvoid_t*)l, 16, 0, 0);
}

// XOR swizzle for 128B-row LDS tiles (kills 16-way ds_read_b128 conflicts)
__device__ __forceinline__ int swz(int row, int colb) {
    return colb ^ ((row & 7) << 4);
}

// ---------------- fused prep: casts + rope tables + lambda ----------------
__device__ __forceinline__ void cast4(const float* __restrict__ s,
                                      u16* __restrict__ d, int u) {
    int i = u * 4;
    float4 v = *(const float4*)(s + i);
    ushort4 o;
    o.x = f2bf(v.x); o.y = f2bf(v.y); o.z = f2bf(v.z); o.w = f2bf(v.w);
    *(ushort4*)(d + i) = o;
}

__global__ __launch_bounds__(256) void prep(const float* __restrict__ x,
                                            const float* __restrict__ Wq,
                                            const float* __restrict__ Wk,
                                            const float* __restrict__ Wv,
                                            const float* __restrict__ Wp,
                                            u16* __restrict__ x_bf, u16* __restrict__ wq_bf,
                                            u16* __restrict__ wk_bf, u16* __restrict__ wv_bf,
                                            u16* __restrict__ wp_bf,
                                            float* __restrict__ cosT, float* __restrict__ sinT,
                                            const float* __restrict__ lq1, const float* __restrict__ lk1,
                                            const float* __restrict__ lq2, const float* __restrict__ lk2,
                                            float* __restrict__ lam) {
    int b = blockIdx.x;
    if (b < 6144) {
        int u = b * 256 + threadIdx.x;
        if (u < 524288)       cast4(x,  x_bf,  u);
        else if (u < 786432)  cast4(Wq, wq_bf, u - 524288);
        else if (u < 1048576) cast4(Wk, wk_bf, u - 786432);
        else if (u < 1310720) cast4(Wv, wv_bf, u - 1048576);
        else                  cast4(Wp, wp_bf, u - 1310720);
    } else if (b < 6400) {
        int i = (b - 6144) * 256 + threadIdx.x;   // < 2048*32
        int t = i >> 5, j = i & 31;
        float inv = powf(10000.0f, -(float)j * (1.0f / 32.0f));
        float fr = (float)t * inv;
        cosT[i] = cosf(fr);
        sinT[i] = sinf(fr);
    } else if (threadIdx.x == 0) {
        float s1 = 0.f, s2 = 0.f;
        for (int i = 0; i < 32; ++i) { s1 += lq1[i] * lk1[i]; s2 += lq2[i] * lk2[i]; }
        *lam = expf(s1) - expf(s2) + 0.35550906759096928f;
    }
}

// ---------------- GEMM tile body: C[M,N] += A[M,K] * B[N,K]^T -------------
// 128x128 tile, BK=32, 4 waves, 16x16x32 bf16 MFMA, global_load_lds w=16.
__device__ __forceinline__ void gemm_tile(const u16* __restrict__ A,
                                          const u16* __restrict__ B,
                                          float* __restrict__ C,
                                          int m0, int n0, int N, int K) {
    __shared__ __align__(16) u16 lA[128 * 32];
    __shared__ __align__(16) u16 lB[128 * 32];
    const int tid = threadIdx.x;
    const int lane = tid & 63;
    const int wid = tid >> 6;
    const int wr = (wid >> 1) * 64;
    const int wc = (wid & 1) * 64;
    const int fr = lane & 15;
    const int kc = lane >> 4;

    f32x4 acc[4][4] = {};
    const char* Ab = (const char*)A;
    const char* Bb = (const char*)B;
    const int rowbytes = K * 2;

    for (int k0 = 0; k0 < K; k0 += 32) {
#pragma unroll
        for (int i = 0; i < 2; ++i) {
            int c = i * 256 + tid;
            gload16(Ab + (size_t)(m0 + (c >> 2)) * rowbytes + k0 * 2 + (c & 3) * 16,
                    (char*)lA + c * 16);
            gload16(Bb + (size_t)(n0 + (c >> 2)) * rowbytes + k0 * 2 + (c & 3) * 16,
                    (char*)lB + c * 16);
        }
        __syncthreads();
        bf16x8 a[4], b[4];
#pragma unroll
        for (int m = 0; m < 4; ++m) a[m] = *(const bf16x8*)&lA[(wr + m * 16 + fr) * 32 + kc * 8];
#pragma unroll
        for (int n = 0; n < 4; ++n) b[n] = *(const bf16x8*)&lB[(wc + n * 16 + fr) * 32 + kc * 8];
#pragma unroll
        for (int m = 0; m < 4; ++m)
#pragma unroll
            for (int n = 0; n < 4; ++n)
                acc[m][n] = __builtin_amdgcn_mfma_f32_16x16x32_bf16(a[m], b[n], acc[m][n], 0, 0, 0);
        __syncthreads();
    }

    const int rr = (lane >> 4) * 4;
#pragma unroll
    for (int m = 0; m < 4; ++m)
#pragma unroll
        for (int n = 0; n < 4; ++n)
#pragma unroll
            for (int r = 0; r < 4; ++r)
                C[(size_t)(m0 + wr + m * 16 + rr + r) * N + (n0 + wc + n * 16 + fr)] = acc[m][n][r];
}

// fused QKV: grid (24,16); x-tiles 0-7 -> Q, 8-15 -> K, 16-23 -> V
__global__ __launch_bounds__(256) void gemm_qkv(const u16* __restrict__ A,
                                                const u16* __restrict__ wq,
                                                const u16* __restrict__ wk,
                                                const u16* __restrict__ wv,
                                                float* __restrict__ Q,
                                                float* __restrict__ K,
                                                float* __restrict__ V) {
    int nt = blockIdx.x;
    int which = nt >> 3;
    const u16* B = (which == 0) ? wq : (which == 1) ? wk : wv;
    float* C = (which == 0) ? Q : (which == 1) ? K : V;
    gemm_tile(A, B, C, blockIdx.y * 128, (nt & 7) * 128, 1024, 1024);
}

__global__ __launch_bounds__(256) void gemm_proj(const u16* __restrict__ A,
                                                 const u16* __restrict__ B,
                                                 float* __restrict__ C) {
    gemm_tile(A, B, C, blockIdx.y * 128, blockIdx.x * 128, 1024, 1024);
}

// ---------------- fused RMS-norm + RoPE, pack to bf16 planes ----------------
__global__ __launch_bounds__(256) void norm_rope(const float* __restrict__ Qf,
                                                 const float* __restrict__ Kf,
                                                 const float* __restrict__ cosT,
                                                 const float* __restrict__ sinT,
                                                 u16* __restrict__ q_bf,
                                                 u16* __restrict__ k_bf) {
    int row = blockIdx.x * 4 + (threadIdx.x >> 6);
    int lane = threadIdx.x & 63;
    int tensor = row >> 15;
    int r = row & 32767;
    int t = r >> 4, p = (r >> 3) & 1, h = r & 7;
    const float* src = (tensor ? Kf : Qf) + (size_t)t * 1024 + p * 512 + h * 64 + lane;
    float x = *src;
    float ss = x * x;
    ss += __shfl_xor(ss, 1);  ss += __shfl_xor(ss, 2);  ss += __shfl_xor(ss, 4);
    ss += __shfl_xor(ss, 8);  ss += __shfl_xor(ss, 16); ss += __shfl_xor(ss, 32);
    float xn = x * rsqrtf(ss * (1.0f / 64.0f) + 1.1920929e-7f);
    float other = __shfl_xor(xn, 32);
    int j = lane & 31;
    float c = cosT[t * 32 + j], s = sinT[t * 32 + j];
    float out = (lane < 32) ? (xn * c + other * s) : (xn * c - other * s);
    u16* dst = (tensor ? k_bf : q_bf) + ((size_t)(p * 8 + h) * T_SEQ + t) * 64 + lane;
    *dst = f2bf(out);
}

// ---------------- V transpose: Vf[t][1024] f32 -> vT[h*128+d][t] bf16 ----------
__global__ __launch_bounds__(256) void vtrans(const float* __restrict__ Vf,
                                              u16* __restrict__ vT) {
    __shared__ float tile[32][33];
    int tx = threadIdx.x & 31;
    int ty = threadIdx.x >> 5;
    int c0 = blockIdx.x * 32;
    int r0 = blockIdx.y * 32;
#pragma unroll
    for (int i = ty; i < 32; i += 8)
        tile[i][tx] = Vf[(size_t)(r0 + i) * 1024 + c0 + tx];
    __syncthreads();
#pragma unroll
    for (int i = ty; i < 32; i += 8)
        vT[(size_t)(c0 + i) * T_SEQ + r0 + tx] = f2bf(tile[tx][i]);
}

// ---------------- flash attention (causal, QBLK=64, KV tile 64) --------------
// grid (32, 8, 2): balanced q-tile x head x variant. 4 waves x 16 q-rows.
// Double-buffered K/V staging; XOR-swizzled LDS.
__global__ __launch_bounds__(256) void attn_kernel(const u16* __restrict__ q_bf,
                                                   const u16* __restrict__ k_bf,
                                                   const u16* __restrict__ vT_bf,
                                                   float* __restrict__ y_out) {
    __shared__ __align__(16) u16 lK[2][64 * 64];
    __shared__ __align__(16) u16 lV[2][128 * 64];
    __shared__ __align__(16) u16 lP[4][16 * 64];

    const int tid = threadIdx.x, lane = tid & 63, wid = tid >> 6;
    const int idx = blockIdx.x, h = blockIdx.y, v = blockIdx.z;
    const int qt = (idx & 1) ? (31 - (idx >> 1)) : (idx >> 1);   // long/short pairing
    const int q0 = qt * 64;
    const int plane = v * 8 + h;
    const u16* qp = q_bf + (size_t)plane * T_SEQ * 64;
    const char* kp = (const char*)(k_bf + (size_t)plane * T_SEQ * 64);
    const char* vp = (const char*)(vT_bf + (size_t)h * 128 * T_SEQ);
    const int fr = lane & 15, kc = lane >> 4, hi = lane >> 4;
    const int wsub = wid * 16;
    char* lPw = (char*)lP[wid];

    // Q fragments held in registers for the whole kernel
    bf16x8 aq[2];
#pragma unroll
    for (int kq = 0; kq < 2; ++kq)
        aq[kq] = *(const bf16x8*)(qp + (size_t)(q0 + wsub + fr) * 64 + kq * 32 + kc * 8);

    f32x4 o[8] = {};
    float mi[4], li[4];
#pragma unroll
    for (int r = 0; r < 4; ++r) { mi[r] = -1e30f; li[r] = 0.f; }

    const float SL = 0.125f * 1.4426950408889634f;   // scale * log2(e)

    auto stage = [&](int b, int s0) {
#pragma unroll
        for (int i = 0; i < 2; ++i) {
            int c = i * 256 + tid;
            int row = c >> 3, cp = (c & 7) * 16;
            gload16(kp + (size_t)(s0 + row) * 128 + swz(row, cp), (char*)lK[b] + c * 16);
        }
#pragma unroll
        for (int i = 0; i < 4; ++i) {
            int c = i * 256 + tid;
            int row = c >> 3, cp = (c & 7) * 16;
            gload16(vp + (size_t)row * (T_SEQ * 2) + (size_t)s0 * 2 + swz(row, cp),
                    (char*)lV[b] + c * 16);
        }
    };

    auto compute = [&](const char* lKb, const char* lVb, int s0, bool diag) {
        f32x4 sacc[4] = {};
#pragma unroll
        for (int kq = 0; kq < 2; ++kq)
#pragma unroll
            for (int n = 0; n < 4; ++n) {
                int row = n * 16 + fr;
                bf16x8 bk = *(const bf16x8*)(lKb + row * 128 + swz(row, kq * 64 + kc * 16));
                sacc[n] = __builtin_amdgcn_mfma_f32_16x16x32_bf16(aq[kq], bk, sacc[n], 0, 0, 0);
            }
#pragma unroll
        for (int r = 0; r < 4; ++r) {
            const int qrow = q0 + wsub + hi * 4 + r;
            float rmax = -1e30f;
#pragma unroll
            for (int n = 0; n < 4; ++n) {
                float sv = sacc[n][r] * SL;
                if (diag && (s0 + n * 16 + fr > qrow)) sv = -1e30f;
                sacc[n][r] = sv;
                rmax = fmaxf(rmax, sv);
            }
            rmax = fmaxf(rmax, __shfl_xor(rmax, 1));
            rmax = fmaxf(rmax, __shfl_xor(rmax, 2));
            rmax = fmaxf(rmax, __shfl_xor(rmax, 4));
            rmax = fmaxf(rmax, __shfl_xor(rmax, 8));
            float mo = mi[r];
            float mn = fmaxf(mo, rmax);
            float f = __builtin_exp2f(mo - mn);
            mi[r] = mn;
            float rs = 0.f;
#pragma unroll
            for (int n = 0; n < 4; ++n) {
                float p = __builtin_exp2f(sacc[n][r] - mn);
                sacc[n][r] = p;
                rs += p;
            }
            rs += __shfl_xor(rs, 1); rs += __shfl_xor(rs, 2);
            rs += __shfl_xor(rs, 4); rs += __shfl_xor(rs, 8);
            li[r] = li[r] * f + rs;
#pragma unroll
            for (int n8 = 0; n8 < 8; ++n8) o[n8][r] *= f;
        }
        // P -> per-wave LDS (swizzled u16 writes)
#pragma unroll
        for (int n = 0; n < 4; ++n)
#pragma unroll
            for (int r = 0; r < 4; ++r) {
                int row = hi * 4 + r;
                *(u16*)(lPw + row * 128 + ((n * 32 + fr * 2) ^ ((row & 7) << 4))) =
                    f2bf(sacc[n][r]);
            }
        // PV: O += P(16x64) * V(64x128)
#pragma unroll
        for (int kk = 0; kk < 2; ++kk) {
            bf16x8 ap = *(const bf16x8*)(lPw + fr * 128 + swz(fr, kk * 64 + kc * 16));
#pragma unroll
            for (int n8 = 0; n8 < 8; ++n8) {
                int row = n8 * 16 + fr;
                bf16x8 bv = *(const bf16x8*)(lVb + row * 128 + swz(row, kk * 64 + kc * 16));
                o[n8] = __builtin_amdgcn_mfma_f32_16x16x32_bf16(ap, bv, o[n8], 0, 0, 0);
            }
        }
    };

    const int nt = qt + 1;
    stage(0, 0);
    __syncthreads();
    for (int t = 0; t < nt; ++t) {
        if (t + 1 < nt) stage((t + 1) & 1, (t + 1) << 6);
        compute((const char*)lK[t & 1], (const char*)lV[t & 1], t << 6, t == nt - 1);
        __syncthreads();
    }

    // epilogue: y_out[v][t][h*128 + d]
#pragma unroll
    for (int r = 0; r < 4; ++r) {
        int t = q0 + wsub + hi * 4 + r;
        float inv_l = 1.0f / li[r];
#pragma unroll
        for (int n8 = 0; n8 < 8; ++n8)
            y_out[(size_t)v * T_SEQ * DMODEL + (size_t)t * DMODEL + h * 128 + n8 * 16 + fr] =
                o[n8][r] * inv_l;
    }
}

// ---------------- combine y1 - lambda*y2 -> bf16 ----------------
__global__ __launch_bounds__(256) void combine(const float* __restrict__ y,
                                               const float* __restrict__ lamp,
                                               u16* __restrict__ yc) {
    int i = (blockIdx.x * 256 + threadIdx.x) * 4;
    float l = *lamp;
    float4 a = *(const float4*)(y + i);
    float4 b = *(const float4*)(y + 2097152 + i);
    ushort4 o;
    o.x = f2bf(a.x - l * b.x);
    o.y = f2bf(a.y - l * b.y);
    o.z = f2bf(a.z - l * b.z);
    o.w = f2bf(a.w - l * b.w);
    *(ushort4*)(yc + i) = o;
}

extern "C" void kernel_launch(void* const* d_in, const int* in_sizes, int n_in,
                              void* d_out, int out_size, void* d_ws, size_t ws_size,
                              hipStream_t stream) {
    const float* x   = (const float*)d_in[0];
    const float* Wq  = (const float*)d_in[1];
    const float* Wk  = (const float*)d_in[2];
    const float* Wv  = (const float*)d_in[3];
    const float* Wp  = (const float*)d_in[4];
    const float* lq1 = (const float*)d_in[5];
    const float* lk1 = (const float*)d_in[6];
    const float* lq2 = (const float*)d_in[7];
    const float* lk2 = (const float*)d_in[8];
    float* out = (float*)d_out;

    char* ws = (char*)d_ws;
    u16*   x_bf  = (u16*)(ws);                         //  4 MB
    u16*   wq_bf = (u16*)(ws + (4ull << 20));          //  2 MB each
    u16*   wk_bf = (u16*)(ws + (6ull << 20));
    u16*   wv_bf = (u16*)(ws + (8ull << 20));
    u16*   wp_bf = (u16*)(ws + (10ull << 20));
    float* Qf    = (float*)(ws + (12ull << 20));       //  8 MB
    float* Kf    = (float*)(ws + (20ull << 20));       //  8 MB
    float* Vf    = (float*)(ws + (28ull << 20));       //  8 MB
    u16*   q_bf  = (u16*)(ws + (36ull << 20));         //  4 MB
    u16*   k_bf  = (u16*)(ws + (40ull << 20));         //  4 MB
    u16*   vT_bf = (u16*)(ws + (44ull << 20));         //  4 MB
    float* y12   = (float*)(ws + (48ull << 20));       // 16 MB
    u16*   yc_bf = (u16*)(ws + (64ull << 20));         //  4 MB
    float* cosT  = (float*)(ws + (68ull << 20));
    float* sinT  = (float*)(ws + (68ull << 20) + (256ull << 10));
    float* lam   = (float*)(ws + (68ull << 20) + (512ull << 10));

    prep<<<6401, 256, 0, stream>>>(x, Wq, Wk, Wv, Wp,
                                   x_bf, wq_bf, wk_bf, wv_bf, wp_bf,
                                   cosT, sinT, lq1, lk1, lq2, lk2, lam);

    gemm_qkv<<<dim3(24, 16), 256, 0, stream>>>(x_bf, wq_bf, wk_bf, wv_bf, Qf, Kf, Vf);

    norm_rope<<<16384, 256, 0, stream>>>(Qf, Kf, cosT, sinT, q_bf, k_bf);
    vtrans<<<dim3(32, 64), 256, 0, stream>>>(Vf, vT_bf);

    attn_kernel<<<dim3(32, 8, 2), 256, 0, stream>>>(q_bf, k_bf, vT_bf, y12);

    combine<<<2048, 256, 0, stream>>>(y12, lam, yc_bf);
    gemm_proj<<<dim3(8, 16), 256, 0, stream>>>(yc_bf, wp_bf, out);
}

// Round 3
// 162.404 us; speedup vs baseline: 1.8708x; 1.0083x over previous
//
#include <hip/hip_runtime.h>
#include <hip/hip_bf16.h>

typedef __attribute__((ext_vector_type(4))) float f32x4;
typedef __attribute__((ext_vector_type(8))) short bf16x8;
typedef unsigned short u16;

#define T_SEQ 2048
#define DMODEL 1024

__device__ __forceinline__ u16 f2bf(float f) {
    __hip_bfloat16 h = __float2bfloat16(f);
    return __builtin_bit_cast(unsigned short, h);
}

typedef const void __attribute__((address_space(1))) gvoid_t;
typedef void __attribute__((address_space(3))) lvoid_t;
__device__ __forceinline__ void gload16(const void* g, void* l) {
    __builtin_amdgcn_global_load_lds((gvoid_t*)g, (lvoid_t*)l, 16, 0, 0);
}

// XOR swizzle for 128B-row LDS tiles (kills 16-way ds_read_b128 conflicts)
__device__ __forceinline__ int swz(int row, int colb) {
    return colb ^ ((row & 7) << 4);
}

// ---------------- fused prep: casts + rope tables + lambda ----------------
__device__ __forceinline__ void cast4(const float* __restrict__ s,
                                      u16* __restrict__ d, int u) {
    int i = u * 4;
    float4 v = *(const float4*)(s + i);
    ushort4 o;
    o.x = f2bf(v.x); o.y = f2bf(v.y); o.z = f2bf(v.z); o.w = f2bf(v.w);
    *(ushort4*)(d + i) = o;
}

__global__ __launch_bounds__(256) void prep(const float* __restrict__ x,
                                            const float* __restrict__ Wq,
                                            const float* __restrict__ Wk,
                                            const float* __restrict__ Wv,
                                            const float* __restrict__ Wp,
                                            u16* __restrict__ x_bf, u16* __restrict__ wq_bf,
                                            u16* __restrict__ wk_bf, u16* __restrict__ wv_bf,
                                            u16* __restrict__ wp_bf,
                                            float* __restrict__ cosT, float* __restrict__ sinT,
                                            const float* __restrict__ lq1, const float* __restrict__ lk1,
                                            const float* __restrict__ lq2, const float* __restrict__ lk2,
                                            float* __restrict__ lam) {
    int b = blockIdx.x;
    if (b < 6144) {
        int u = b * 256 + threadIdx.x;
        if (u < 524288)       cast4(x,  x_bf,  u);
        else if (u < 786432)  cast4(Wq, wq_bf, u - 524288);
        else if (u < 1048576) cast4(Wk, wk_bf, u - 786432);
        else if (u < 1310720) cast4(Wv, wv_bf, u - 1048576);
        else                  cast4(Wp, wp_bf, u - 1310720);
    } else if (b < 6400) {
        int i = (b - 6144) * 256 + threadIdx.x;   // < 2048*32
        int t = i >> 5, j = i & 31;
        float inv = powf(10000.0f, -(float)j * (1.0f / 32.0f));
        float fr = (float)t * inv;
        cosT[i] = cosf(fr);
        sinT[i] = sinf(fr);
    } else if (threadIdx.x == 0) {
        float s1 = 0.f, s2 = 0.f;
        for (int i = 0; i < 32; ++i) { s1 += lq1[i] * lk1[i]; s2 += lq2[i] * lk2[i]; }
        *lam = expf(s1) - expf(s2) + 0.35550906759096928f;
    }
}

// ---------------- GEMM main loop: acc = A[M,K] * B[N,K]^T (128x128 tile) ------
__device__ __forceinline__ void gemm_main(const u16* __restrict__ A,
                                          const u16* __restrict__ B,
                                          int m0, int n0, int K,
                                          u16* lA, u16* lB, f32x4 acc[4][4]) {
    const int tid = threadIdx.x;
    const int lane = tid & 63;
    const int wid = tid >> 6;
    const int wr = (wid >> 1) * 64;
    const int wc = (wid & 1) * 64;
    const int fr = lane & 15;
    const int kc = lane >> 4;
    const char* Ab = (const char*)A;
    const char* Bb = (const char*)B;
    const int rowbytes = K * 2;

    for (int k0 = 0; k0 < K; k0 += 32) {
#pragma unroll
        for (int i = 0; i < 2; ++i) {
            int c = i * 256 + tid;
            gload16(Ab + (size_t)(m0 + (c >> 2)) * rowbytes + k0 * 2 + (c & 3) * 16,
                    (char*)lA + c * 16);
            gload16(Bb + (size_t)(n0 + (c >> 2)) * rowbytes + k0 * 2 + (c & 3) * 16,
                    (char*)lB + c * 16);
        }
        __syncthreads();
        bf16x8 a[4], b[4];
#pragma unroll
        for (int m = 0; m < 4; ++m) a[m] = *(const bf16x8*)&lA[(wr + m * 16 + fr) * 32 + kc * 8];
#pragma unroll
        for (int n = 0; n < 4; ++n) b[n] = *(const bf16x8*)&lB[(wc + n * 16 + fr) * 32 + kc * 8];
#pragma unroll
        for (int m = 0; m < 4; ++m)
#pragma unroll
            for (int n = 0; n < 4; ++n)
                acc[m][n] = __builtin_amdgcn_mfma_f32_16x16x32_bf16(a[m], b[n], acc[m][n], 0, 0, 0);
        __syncthreads();
    }
}

// fused QKV GEMM: x-tiles 0-7 -> Q, 8-15 -> K, 16-23 -> V.
// Q/K epilogue: RMS-norm + RoPE fused, writes bf16 planes [p*8+h][t][64].
// V epilogue: cast to bf16 [t][1024].
__global__ __launch_bounds__(256) void gemm_qkv(const u16* __restrict__ A,
                                                const u16* __restrict__ wq,
                                                const u16* __restrict__ wk,
                                                const u16* __restrict__ wv,
                                                const float* __restrict__ cosT,
                                                const float* __restrict__ sinT,
                                                u16* __restrict__ q_bf,
                                                u16* __restrict__ k_bf,
                                                u16* __restrict__ Vbf) {
    __shared__ __align__(16) u16 lA[128 * 32];
    __shared__ __align__(16) u16 lB[128 * 32];
    const int nt = blockIdx.x;
    const int which = nt >> 3;
    const u16* B = (which == 0) ? wq : (which == 1) ? wk : wv;
    const int m0 = blockIdx.y * 128;
    const int n0 = (nt & 7) * 128;

    f32x4 acc[4][4] = {};
    gemm_main(A, B, m0, n0, 1024, lA, lB, acc);

    const int lane = threadIdx.x & 63;
    const int wid = threadIdx.x >> 6;
    const int wr = (wid >> 1) * 64;
    const int wc = (wid & 1) * 64;
    const int fr = lane & 15;
    const int rr = (lane >> 4) * 4;

    if (which == 2) {
#pragma unroll
        for (int m = 0; m < 4; ++m)
#pragma unroll
            for (int n = 0; n < 4; ++n)
#pragma unroll
                for (int r = 0; r < 4; ++r)
                    Vbf[(size_t)(m0 + wr + m * 16 + rr + r) * 1024 + n0 + wc + n * 16 + fr] =
                        f2bf(acc[m][n][r]);
        return;
    }

    // Q/K: this wave's 64 cols = one (variant p, head h)
    const int cb = n0 + wc;
    const int plane = ((cb >> 9) << 3) | ((cb >> 6) & 7);
    u16* dstp = ((which == 0) ? q_bf : k_bf) + (size_t)plane * T_SEQ * 64;
#pragma unroll
    for (int m = 0; m < 4; ++m)
#pragma unroll
        for (int r = 0; r < 4; ++r) {
            int t = m0 + wr + m * 16 + rr + r;
            float s2 = 0.f;
#pragma unroll
            for (int n = 0; n < 4; ++n) { float a = acc[m][n][r]; s2 += a * a; }
            s2 += __shfl_xor(s2, 1); s2 += __shfl_xor(s2, 2);
            s2 += __shfl_xor(s2, 4); s2 += __shfl_xor(s2, 8);
            float inv = rsqrtf(s2 * (1.0f / 64.0f) + 1.1920929e-7f);
#pragma unroll
            for (int n = 0; n < 4; ++n) {
                float a = acc[m][n][r] * inv;
                float p_ = acc[m][n ^ 2][r] * inv;
                int jj = ((n & 1) << 4) + fr;
                float c = cosT[t * 32 + jj], sn = sinT[t * 32 + jj];
                float ov = (n < 2) ? (a * c + p_ * sn) : (a * c - p_ * sn);
                dstp[(size_t)t * 64 + n * 16 + fr] = f2bf(ov);
            }
        }
}

__global__ __launch_bounds__(256) void gemm_proj(const u16* __restrict__ A,
                                                 const u16* __restrict__ B,
                                                 float* __restrict__ C) {
    __shared__ __align__(16) u16 lA[128 * 32];
    __shared__ __align__(16) u16 lB[128 * 32];
    const int m0 = blockIdx.y * 128;
    const int n0 = blockIdx.x * 128;
    f32x4 acc[4][4] = {};
    gemm_main(A, B, m0, n0, 1024, lA, lB, acc);
    const int lane = threadIdx.x & 63;
    const int wid = threadIdx.x >> 6;
    const int wr = (wid >> 1) * 64;
    const int wc = (wid & 1) * 64;
    const int fr = lane & 15;
    const int rr = (lane >> 4) * 4;
#pragma unroll
    for (int m = 0; m < 4; ++m)
#pragma unroll
        for (int n = 0; n < 4; ++n)
#pragma unroll
            for (int r = 0; r < 4; ++r)
                C[(size_t)(m0 + wr + m * 16 + rr + r) * 1024 + (n0 + wc + n * 16 + fr)] =
                    acc[m][n][r];
}

// ---------------- V transpose (bf16): Vbf[t][1024] -> vT[h*128+d][t] ----------
__global__ __launch_bounds__(256) void vtrans(const u16* __restrict__ Vbf,
                                              u16* __restrict__ vT) {
    __shared__ u16 tile[32][34];
    int tx = threadIdx.x & 31;
    int ty = threadIdx.x >> 5;
    int c0 = blockIdx.x * 32;
    int r0 = blockIdx.y * 32;
#pragma unroll
    for (int i = ty; i < 32; i += 8)
        tile[i][tx] = Vbf[(size_t)(r0 + i) * 1024 + c0 + tx];
    __syncthreads();
#pragma unroll
    for (int i = ty; i < 32; i += 8)
        vT[(size_t)(c0 + i) * T_SEQ + r0 + tx] = tile[tx][i];
}

// ---------------- flash attention (causal, QBLK=64, KV tile 64, KV-split x2) --
// grid (64, 8, 2): x = (qt desc, chunk), y = head, z = variant. 4 waves x 16 rows.
// Writes unnormalized O (f32) + per-row (m, l) in exp2 domain.
__global__ __launch_bounds__(256) void attn_kernel(const u16* __restrict__ q_bf,
                                                   const u16* __restrict__ k_bf,
                                                   const u16* __restrict__ vT_bf,
                                                   float* __restrict__ Oc,
                                                   float* __restrict__ ml) {
    __shared__ __align__(16) u16 lK[2][64 * 64];
    __shared__ __align__(16) u16 lV[2][128 * 64];
    __shared__ __align__(16) u16 lP[4][16 * 64];

    const int tid = threadIdx.x, lane = tid & 63, wid = tid >> 6;
    const int bx = blockIdx.x, h = blockIdx.y, v = blockIdx.z;
    const int qt = 31 - (bx >> 1), chunk = bx & 1;
    const int q0 = qt * 64;
    const int plane = v * 8 + h;
    const int nt = qt + 1;
    const int h1 = (nt + 1) >> 1;
    const int t0 = chunk ? h1 : 0;
    const int t1 = chunk ? nt : h1;
    const size_t mlbase = ((size_t)(chunk * 16 + plane) * T_SEQ + q0);

    if (t0 >= t1) {   // empty chunk: sentinel (m=-inf, l=0); merge zeroes it out
        if (tid < 64) {
            ml[(mlbase + tid) * 2] = -1e30f;
            ml[(mlbase + tid) * 2 + 1] = 0.f;
        }
        return;
    }

    const u16* qp = q_bf + (size_t)plane * T_SEQ * 64;
    const char* kp = (const char*)(k_bf + (size_t)plane * T_SEQ * 64);
    const char* vp = (const char*)(vT_bf + (size_t)h * 128 * T_SEQ);
    const int fr = lane & 15, kc = lane >> 4, hi = lane >> 4;
    const int wsub = wid * 16;
    char* lPw = (char*)lP[wid];

    bf16x8 aq[2];
#pragma unroll
    for (int kq = 0; kq < 2; ++kq)
        aq[kq] = *(const bf16x8*)(qp + (size_t)(q0 + wsub + fr) * 64 + kq * 32 + kc * 8);

    f32x4 o[8] = {};
    float mi[4], li[4];
#pragma unroll
    for (int r = 0; r < 4; ++r) { mi[r] = -1e30f; li[r] = 0.f; }

    const float SL = 0.125f * 1.4426950408889634f;   // scale * log2(e)

    auto stage = [&](int b, int s0) {
#pragma unroll
        for (int i = 0; i < 2; ++i) {
            int c = i * 256 + tid;
            int row = c >> 3, cp = (c & 7) * 16;
            gload16(kp + (size_t)(s0 + row) * 128 + swz(row, cp), (char*)lK[b] + c * 16);
        }
#pragma unroll
        for (int i = 0; i < 4; ++i) {
            int c = i * 256 + tid;
            int row = c >> 3, cp = (c & 7) * 16;
            gload16(vp + (size_t)row * (T_SEQ * 2) + (size_t)s0 * 2 + swz(row, cp),
                    (char*)lV[b] + c * 16);
        }
    };

    auto compute = [&](const char* lKb, const char* lVb, int s0, bool diag) {
        f32x4 sacc[4] = {};
#pragma unroll
        for (int kq = 0; kq < 2; ++kq)
#pragma unroll
            for (int n = 0; n < 4; ++n) {
                int row = n * 16 + fr;
                bf16x8 bk = *(const bf16x8*)(lKb + row * 128 + swz(row, kq * 64 + kc * 16));
                sacc[n] = __builtin_amdgcn_mfma_f32_16x16x32_bf16(aq[kq], bk, sacc[n], 0, 0, 0);
            }
#pragma unroll
        for (int r = 0; r < 4; ++r) {
            const int qrow = q0 + wsub + hi * 4 + r;
            float rmax = -1e30f;
#pragma unroll
            for (int n = 0; n < 4; ++n) {
                float sv = sacc[n][r] * SL;
                if (diag && (s0 + n * 16 + fr > qrow)) sv = -1e30f;
                sacc[n][r] = sv;
                rmax = fmaxf(rmax, sv);
            }
            rmax = fmaxf(rmax, __shfl_xor(rmax, 1));
            rmax = fmaxf(rmax, __shfl_xor(rmax, 2));
            rmax = fmaxf(rmax, __shfl_xor(rmax, 4));
            rmax = fmaxf(rmax, __shfl_xor(rmax, 8));
            float mo = mi[r];
            float mn = fmaxf(mo, rmax);
            float f = __builtin_exp2f(mo - mn);
            mi[r] = mn;
            float rs = 0.f;
#pragma unroll
            for (int n = 0; n < 4; ++n) {
                float p = __builtin_exp2f(sacc[n][r] - mn);
                sacc[n][r] = p;
                rs += p;
            }
            rs += __shfl_xor(rs, 1); rs += __shfl_xor(rs, 2);
            rs += __shfl_xor(rs, 4); rs += __shfl_xor(rs, 8);
            li[r] = li[r] * f + rs;
#pragma unroll
            for (int n8 = 0; n8 < 8; ++n8) o[n8][r] *= f;
        }
#pragma unroll
        for (int n = 0; n < 4; ++n)
#pragma unroll
            for (int r = 0; r < 4; ++r) {
                int row = hi * 4 + r;
                *(u16*)(lPw + row * 128 + ((n * 32 + fr * 2) ^ ((row & 7) << 4))) =
                    f2bf(sacc[n][r]);
            }
#pragma unroll
        for (int kk = 0; kk < 2; ++kk) {
            bf16x8 ap = *(const bf16x8*)(lPw + fr * 128 + swz(fr, kk * 64 + kc * 16));
#pragma unroll
            for (int n8 = 0; n8 < 8; ++n8) {
                int row = n8 * 16 + fr;
                bf16x8 bv = *(const bf16x8*)(lVb + row * 128 + swz(row, kk * 64 + kc * 16));
                o[n8] = __builtin_amdgcn_mfma_f32_16x16x32_bf16(ap, bv, o[n8], 0, 0, 0);
            }
        }
    };

    stage(0, t0 << 6);
    __syncthreads();
    for (int t = t0; t < t1; ++t) {
        if (t + 1 < t1) stage((t - t0 + 1) & 1, (t + 1) << 6);
        compute((const char*)lK[(t - t0) & 1], (const char*)lV[(t - t0) & 1],
                t << 6, t == nt - 1);
        __syncthreads();
    }

    // epilogue: unnormalized O + (m,l)
    float* Ob = Oc + (size_t)(chunk * 16 + plane) * T_SEQ * 128;
#pragma unroll
    for (int r = 0; r < 4; ++r) {
        int t = q0 + wsub + hi * 4 + r;
#pragma unroll
        for (int n8 = 0; n8 < 8; ++n8)
            Ob[(size_t)t * 128 + n8 * 16 + fr] = o[n8][r];
    }
    if (fr == 0) {
#pragma unroll
        for (int r = 0; r < 4; ++r) {
            size_t mb = (mlbase + wsub + hi * 4 + r) * 2;
            ml[mb] = mi[r];
            ml[mb + 1] = li[r];
        }
    }
}

// ---------------- merge chunks + diff (y1 - lambda*y2) -> bf16 ----------------
__global__ __launch_bounds__(256) void merge_kernel(const float* __restrict__ Oc,
                                                    const float* __restrict__ ml,
                                                    const float* __restrict__ lamp,
                                                    u16* __restrict__ yc) {
    int u = blockIdx.x * 256 + threadIdx.x;   // < 524288
    int t = u >> 8, rem = u & 255, h = rem >> 5, d4 = (rem & 31) * 4;
    float lamv = *lamp;
    float yv[2][4];
#pragma unroll
    for (int v = 0; v < 2; ++v) {
        int plane = v * 8 + h;
        size_t b0 = (size_t)plane * T_SEQ + t;
        size_t b1 = (size_t)(16 + plane) * T_SEQ + t;
        float m0 = ml[b0 * 2], l0 = ml[b0 * 2 + 1];
        float m1 = ml[b1 * 2], l1 = ml[b1 * 2 + 1];
        float mm = fmaxf(m0, m1);
        float w0 = __builtin_exp2f(m0 - mm);
        float w1 = __builtin_exp2f(m1 - mm);
        float inv = 1.0f / (l0 * w0 + l1 * w1);
        float4 O0 = *(const float4*)(Oc + b0 * 128 + d4);
        float4 O1 = *(const float4*)(Oc + b1 * 128 + d4);
        yv[v][0] = (O0.x * w0 + O1.x * w1) * inv;
        yv[v][1] = (O0.y * w0 + O1.y * w1) * inv;
        yv[v][2] = (O0.z * w0 + O1.z * w1) * inv;
        yv[v][3] = (O0.w * w0 + O1.w * w1) * inv;
    }
    ushort4 o;
    o.x = f2bf(yv[0][0] - lamv * yv[1][0]);
    o.y = f2bf(yv[0][1] - lamv * yv[1][1]);
    o.z = f2bf(yv[0][2] - lamv * yv[1][2]);
    o.w = f2bf(yv[0][3] - lamv * yv[1][3]);
    *(ushort4*)(yc + (size_t)t * 1024 + h * 128 + d4) = o;
}

extern "C" void kernel_launch(void* const* d_in, const int* in_sizes, int n_in,
                              void* d_out, int out_size, void* d_ws, size_t ws_size,
                              hipStream_t stream) {
    const float* x   = (const float*)d_in[0];
    const float* Wq  = (const float*)d_in[1];
    const float* Wk  = (const float*)d_in[2];
    const float* Wv  = (const float*)d_in[3];
    const float* Wp  = (const float*)d_in[4];
    const float* lq1 = (const float*)d_in[5];
    const float* lk1 = (const float*)d_in[6];
    const float* lq2 = (const float*)d_in[7];
    const float* lk2 = (const float*)d_in[8];
    float* out = (float*)d_out;

    char* ws = (char*)d_ws;
    u16*   x_bf  = (u16*)(ws);                         //  4 MB
    u16*   wq_bf = (u16*)(ws + (4ull << 20));
    u16*   wk_bf = (u16*)(ws + (6ull << 20));
    u16*   wv_bf = (u16*)(ws + (8ull << 20));
    u16*   wp_bf = (u16*)(ws + (10ull << 20));
    u16*   Vbf   = (u16*)(ws + (12ull << 20));         //  4 MB
    u16*   q_bf  = (u16*)(ws + (16ull << 20));         //  4 MB
    u16*   k_bf  = (u16*)(ws + (20ull << 20));         //  4 MB
    u16*   vT_bf = (u16*)(ws + (24ull << 20));         //  4 MB
    float* Oc    = (float*)(ws + (28ull << 20));       // 32 MB
    float* ml    = (float*)(ws + (60ull << 20));       // 512 KB
    float* cosT  = (float*)(ws + (61ull << 20));
    float* sinT  = (float*)(ws + (61ull << 20) + (256ull << 10));
    float* lam   = (float*)(ws + (61ull << 20) + (512ull << 10));
    u16*   yc_bf = (u16*)(ws + (62ull << 20));         //  4 MB

    prep<<<6401, 256, 0, stream>>>(x, Wq, Wk, Wv, Wp,
                                   x_bf, wq_bf, wk_bf, wv_bf, wp_bf,
                                   cosT, sinT, lq1, lk1, lq2, lk2, lam);

    gemm_qkv<<<dim3(24, 16), 256, 0, stream>>>(x_bf, wq_bf, wk_bf, wv_bf,
                                               cosT, sinT, q_bf, k_bf, Vbf);

    vtrans<<<dim3(32, 64), 256, 0, stream>>>(Vbf, vT_bf);

    attn_kernel<<<dim3(64, 8, 2), 256, 0, stream>>>(q_bf, k_bf, vT_bf, Oc, ml);

    merge_kernel<<<2048, 256, 0, stream>>>(Oc, ml, lam, yc_bf);

    gemm_proj<<<dim3(8, 16), 256, 0, stream>>>(yc_bf, wp_bf, out);
}

// Round 4
// 137.242 us; speedup vs baseline: 2.2138x; 1.1833x over previous
//
#include <hip/hip_runtime.h>
#include <hip/hip_bf16.h>

typedef __attribute__((ext_vector_type(4))) float f32x4;
typedef __attribute__((ext_vector_type(8))) short bf16x8;
typedef unsigned short u16;

#define T_SEQ 2048
#define DMODEL 1024

__device__ __forceinline__ u16 f2bf(float f) {
    __hip_bfloat16 h = __float2bfloat16(f);
    return __builtin_bit_cast(unsigned short, h);
}

typedef const void __attribute__((address_space(1))) gvoid_t;
typedef void __attribute__((address_space(3))) lvoid_t;
__device__ __forceinline__ void gload16(const void* g, void* l) {
    __builtin_amdgcn_global_load_lds((gvoid_t*)g, (lvoid_t*)l, 16, 0, 0);
}

// XOR swizzle for 128B-row LDS tiles (kills 16-way ds_read_b128 conflicts)
__device__ __forceinline__ int swz(int row, int colb) {
    return colb ^ ((row & 7) << 4);
}

// ---------------- fused prep: casts + rope tables + lambda ----------------
__device__ __forceinline__ void cast4(const float* __restrict__ s,
                                      u16* __restrict__ d, int u) {
    int i = u * 4;
    float4 v = *(const float4*)(s + i);
    ushort4 o;
    o.x = f2bf(v.x); o.y = f2bf(v.y); o.z = f2bf(v.z); o.w = f2bf(v.w);
    *(ushort4*)(d + i) = o;
}

__global__ __launch_bounds__(256) void prep(const float* __restrict__ x,
                                            const float* __restrict__ Wq,
                                            const float* __restrict__ Wk,
                                            const float* __restrict__ Wv,
                                            const float* __restrict__ Wp,
                                            u16* __restrict__ x_bf, u16* __restrict__ wq_bf,
                                            u16* __restrict__ wk_bf, u16* __restrict__ wv_bf,
                                            u16* __restrict__ wp_bf,
                                            float* __restrict__ cosT, float* __restrict__ sinT,
                                            const float* __restrict__ lq1, const float* __restrict__ lk1,
                                            const float* __restrict__ lq2, const float* __restrict__ lk2,
                                            float* __restrict__ lam) {
    int b = blockIdx.x;
    if (b < 6144) {
        int u = b * 256 + threadIdx.x;
        if (u < 524288)       cast4(x,  x_bf,  u);
        else if (u < 786432)  cast4(Wq, wq_bf, u - 524288);
        else if (u < 1048576) cast4(Wk, wk_bf, u - 786432);
        else if (u < 1310720) cast4(Wv, wv_bf, u - 1048576);
        else                  cast4(Wp, wp_bf, u - 1310720);
    } else if (b < 6400) {
        int i = (b - 6144) * 256 + threadIdx.x;   // < 2048*32
        int t = i >> 5, j = i & 31;
        float inv = powf(10000.0f, -(float)j * (1.0f / 32.0f));
        float fr = (float)t * inv;
        cosT[i] = cosf(fr);
        sinT[i] = sinf(fr);
    } else if (threadIdx.x == 0) {
        float s1 = 0.f, s2 = 0.f;
        for (int i = 0; i < 32; ++i) { s1 += lq1[i] * lk1[i]; s2 += lq2[i] * lk2[i]; }
        *lam = expf(s1) - expf(s2) + 0.35550906759096928f;
    }
}

// ---------------- GEMM main loop: acc = A[M,K] * B[N,K]^T (128x128 tile) ------
__device__ __forceinline__ void gemm_main(const u16* __restrict__ A,
                                          const u16* __restrict__ B,
                                          int m0, int n0, int K,
                                          u16* lA, u16* lB, f32x4 acc[4][4]) {
    const int tid = threadIdx.x;
    const int lane = tid & 63;
    const int wid = tid >> 6;
    const int wr = (wid >> 1) * 64;
    const int wc = (wid & 1) * 64;
    const int fr = lane & 15;
    const int kc = lane >> 4;
    const char* Ab = (const char*)A;
    const char* Bb = (const char*)B;
    const int rowbytes = K * 2;

    for (int k0 = 0; k0 < K; k0 += 32) {
#pragma unroll
        for (int i = 0; i < 2; ++i) {
            int c = i * 256 + tid;
            gload16(Ab + (size_t)(m0 + (c >> 2)) * rowbytes + k0 * 2 + (c & 3) * 16,
                    (char*)lA + c * 16);
            gload16(Bb + (size_t)(n0 + (c >> 2)) * rowbytes + k0 * 2 + (c & 3) * 16,
                    (char*)lB + c * 16);
        }
        __syncthreads();
        bf16x8 a[4], b[4];
#pragma unroll
        for (int m = 0; m < 4; ++m) a[m] = *(const bf16x8*)&lA[(wr + m * 16 + fr) * 32 + kc * 8];
#pragma unroll
        for (int n = 0; n < 4; ++n) b[n] = *(const bf16x8*)&lB[(wc + n * 16 + fr) * 32 + kc * 8];
#pragma unroll
        for (int m = 0; m < 4; ++m)
#pragma unroll
            for (int n = 0; n < 4; ++n)
                acc[m][n] = __builtin_amdgcn_mfma_f32_16x16x32_bf16(a[m], b[n], acc[m][n], 0, 0, 0);
        __syncthreads();
    }
}

// fused QKV GEMM: x-tiles 0-7 -> Q, 8-15 -> K, 16-23 -> V.
// Q/K epilogue: RMS-norm + RoPE fused, writes bf16 planes [p*8+h][t][64].
// V epilogue: cast to bf16 [t][1024].
__global__ __launch_bounds__(256) void gemm_qkv(const u16* __restrict__ A,
                                                const u16* __restrict__ wq,
                                                const u16* __restrict__ wk,
                                                const u16* __restrict__ wv,
                                                const float* __restrict__ cosT,
                                                const float* __restrict__ sinT,
                                                u16* __restrict__ q_bf,
                                                u16* __restrict__ k_bf,
                                                u16* __restrict__ Vbf) {
    __shared__ __align__(16) u16 lA[128 * 32];
    __shared__ __align__(16) u16 lB[128 * 32];
    const int nt = blockIdx.x;
    const int which = nt >> 3;
    const u16* B = (which == 0) ? wq : (which == 1) ? wk : wv;
    const int m0 = blockIdx.y * 128;
    const int n0 = (nt & 7) * 128;

    f32x4 acc[4][4] = {};
    gemm_main(A, B, m0, n0, 1024, lA, lB, acc);

    const int lane = threadIdx.x & 63;
    const int wid = threadIdx.x >> 6;
    const int wr = (wid >> 1) * 64;
    const int wc = (wid & 1) * 64;
    const int fr = lane & 15;
    const int rr = (lane >> 4) * 4;

    if (which == 2) {
#pragma unroll
        for (int m = 0; m < 4; ++m)
#pragma unroll
            for (int n = 0; n < 4; ++n)
#pragma unroll
                for (int r = 0; r < 4; ++r)
                    Vbf[(size_t)(m0 + wr + m * 16 + rr + r) * 1024 + n0 + wc + n * 16 + fr] =
                        f2bf(acc[m][n][r]);
        return;
    }

    // Q/K: this wave's 64 cols = one (variant p, head h)
    const int cb = n0 + wc;
    const int plane = ((cb >> 9) << 3) | ((cb >> 6) & 7);
    u16* dstp = ((which == 0) ? q_bf : k_bf) + (size_t)plane * T_SEQ * 64;
#pragma unroll
    for (int m = 0; m < 4; ++m)
#pragma unroll
        for (int r = 0; r < 4; ++r) {
            int t = m0 + wr + m * 16 + rr + r;
            float s2 = 0.f;
#pragma unroll
            for (int n = 0; n < 4; ++n) { float a = acc[m][n][r]; s2 += a * a; }
            s2 += __shfl_xor(s2, 1); s2 += __shfl_xor(s2, 2);
            s2 += __shfl_xor(s2, 4); s2 += __shfl_xor(s2, 8);
            float inv = rsqrtf(s2 * (1.0f / 64.0f) + 1.1920929e-7f);
#pragma unroll
            for (int n = 0; n < 4; ++n) {
                float a = acc[m][n][r] * inv;
                float p_ = acc[m][n ^ 2][r] * inv;
                int jj = ((n & 1) << 4) + fr;
                float c = cosT[t * 32 + jj], sn = sinT[t * 32 + jj];
                float ov = (n < 2) ? (a * c + p_ * sn) : (a * c - p_ * sn);
                dstp[(size_t)t * 64 + n * 16 + fr] = f2bf(ov);
            }
        }
}

__global__ __launch_bounds__(256) void gemm_proj(const u16* __restrict__ A,
                                                 const u16* __restrict__ B,
                                                 float* __restrict__ C) {
    __shared__ __align__(16) u16 lA[128 * 32];
    __shared__ __align__(16) u16 lB[128 * 32];
    const int m0 = blockIdx.y * 128;
    const int n0 = blockIdx.x * 128;
    f32x4 acc[4][4] = {};
    gemm_main(A, B, m0, n0, 1024, lA, lB, acc);
    const int lane = threadIdx.x & 63;
    const int wid = threadIdx.x >> 6;
    const int wr = (wid >> 1) * 64;
    const int wc = (wid & 1) * 64;
    const int fr = lane & 15;
    const int rr = (lane >> 4) * 4;
#pragma unroll
    for (int m = 0; m < 4; ++m)
#pragma unroll
        for (int n = 0; n < 4; ++n)
#pragma unroll
            for (int r = 0; r < 4; ++r)
                C[(size_t)(m0 + wr + m * 16 + rr + r) * 1024 + (n0 + wc + n * 16 + fr)] =
                    acc[m][n][r];
}

// ---------------- V transpose (bf16): Vbf[t][1024] -> vT[h*128+d][t] ----------
__global__ __launch_bounds__(256) void vtrans(const u16* __restrict__ Vbf,
                                              u16* __restrict__ vT) {
    __shared__ u16 tile[32][34];
    int tx = threadIdx.x & 31;
    int ty = threadIdx.x >> 5;
    int c0 = blockIdx.x * 32;
    int r0 = blockIdx.y * 32;
#pragma unroll
    for (int i = ty; i < 32; i += 8)
        tile[i][tx] = Vbf[(size_t)(r0 + i) * 1024 + c0 + tx];
    __syncthreads();
#pragma unroll
    for (int i = ty; i < 32; i += 8)
        vT[(size_t)(c0 + i) * T_SEQ + r0 + tx] = tile[tx][i];
}

// ---------------- flash attention (causal, QBLK=64, KV tile 64) --------------
// grid (32, 8, 2): paired q-tiles x head x variant. 4 waves x 16 q-rows.
// Swapped QK^T (S^T = K·Q^T): each lane owns one q-row -> lane-local softmax.
__global__ __launch_bounds__(256) void attn_kernel(const u16* __restrict__ q_bf,
                                                   const u16* __restrict__ k_bf,
                                                   const u16* __restrict__ vT_bf,
                                                   float* __restrict__ y_out) {
    __shared__ __align__(16) u16 lK[2][64 * 64];
    __shared__ __align__(16) u16 lV[2][128 * 64];
    __shared__ __align__(16) u16 lP[4][16 * 64];

    const int tid = threadIdx.x, lane = tid & 63, wid = tid >> 6;
    const int idx = blockIdx.x, h = blockIdx.y, v = blockIdx.z;
    const int qt = (idx & 1) ? (31 - (idx >> 1)) : (idx >> 1);   // long/short pairing
    const int q0 = qt * 64;
    const int plane = v * 8 + h;
    const u16* qp = q_bf + (size_t)plane * T_SEQ * 64;
    const char* kp = (const char*)(k_bf + (size_t)plane * T_SEQ * 64);
    const char* vp = (const char*)(vT_bf + (size_t)h * 128 * T_SEQ);
    const int fr = lane & 15, kc = lane >> 4;
    const int wsub = wid * 16;
    char* lPw = (char*)lP[wid];

    // Q fragments held in registers for the whole kernel (also B-operand layout)
    bf16x8 aq[2];
#pragma unroll
    for (int kq = 0; kq < 2; ++kq)
        aq[kq] = *(const bf16x8*)(qp + (size_t)(q0 + wsub + fr) * 64 + kq * 32 + kc * 8);

    f32x4 o[8] = {};
    float mi_l = -1e30f, li_l = 0.f;   // per-lane: q-row = q0+wsub+fr

    const float SL = 0.125f * 1.4426950408889634f;   // scale * log2(e)
    const int qrow = q0 + wsub + fr;

    auto stage = [&](int b, int s0) {
#pragma unroll
        for (int i = 0; i < 2; ++i) {
            int c = i * 256 + tid;
            int row = c >> 3, cp = (c & 7) * 16;
            gload16(kp + (size_t)(s0 + row) * 128 + swz(row, cp), (char*)lK[b] + c * 16);
        }
#pragma unroll
        for (int i = 0; i < 4; ++i) {
            int c = i * 256 + tid;
            int row = c >> 3, cp = (c & 7) * 16;
            gload16(vp + (size_t)row * (T_SEQ * 2) + (size_t)s0 * 2 + swz(row, cp),
                    (char*)lV[b] + c * 16);
        }
    };

    auto compute = [&](const char* lKb, const char* lVb, int s0, bool diag) {
        // S^T: A = K rows, B = Q rows. sacc[n][r] = S[s0+n*16+kc*4+r][qrow]
        f32x4 sacc[4] = {};
        __builtin_amdgcn_s_setprio(1);
#pragma unroll
        for (int kq = 0; kq < 2; ++kq)
#pragma unroll
            for (int n = 0; n < 4; ++n) {
                int row = n * 16 + fr;
                bf16x8 bk = *(const bf16x8*)(lKb + row * 128 + swz(row, kq * 64 + kc * 16));
                sacc[n] = __builtin_amdgcn_mfma_f32_16x16x32_bf16(bk, aq[kq], sacc[n], 0, 0, 0);
            }
        __builtin_amdgcn_s_setprio(0);

        // lane-local softmax over 16 values (+2 cross-lane shfls)
        float rmax = -1e30f;
#pragma unroll
        for (int n = 0; n < 4; ++n)
#pragma unroll
            for (int r = 0; r < 4; ++r) {
                float sv = sacc[n][r] * SL;
                if (diag && (s0 + n * 16 + kc * 4 + r > qrow)) sv = -1e30f;
                sacc[n][r] = sv;
                rmax = fmaxf(rmax, sv);
            }
        rmax = fmaxf(rmax, __shfl_xor(rmax, 16));
        rmax = fmaxf(rmax, __shfl_xor(rmax, 32));
        float mn = fmaxf(mi_l, rmax);
        float f = __builtin_exp2f(mi_l - mn);
        mi_l = mn;
        float rs = 0.f;
#pragma unroll
        for (int n = 0; n < 4; ++n)
#pragma unroll
            for (int r = 0; r < 4; ++r) {
                float p = __builtin_exp2f(sacc[n][r] - mn);
                sacc[n][r] = p;
                rs += p;
            }
        rs += __shfl_xor(rs, 16);
        rs += __shfl_xor(rs, 32);
        li_l = li_l * f + rs;

        // broadcast rescale factor into O's (kc,r) row indexing, rescale O
#pragma unroll
        for (int r = 0; r < 4; ++r) {
            float fb = __shfl(f, kc * 4 + r);
#pragma unroll
            for (int n8 = 0; n8 < 8; ++n8) o[n8][r] *= fb;
        }

        // P -> LDS: row q=fr, 4 k-consecutive bf16 per write (b64), swizzled
#pragma unroll
        for (int n = 0; n < 4; ++n) {
            ushort4 pk;
            pk.x = f2bf(sacc[n][0]); pk.y = f2bf(sacc[n][1]);
            pk.z = f2bf(sacc[n][2]); pk.w = f2bf(sacc[n][3]);
            *(ushort4*)(lPw + fr * 128 + ((n * 32 + kc * 8) ^ ((fr & 7) << 4))) = pk;
        }

        // PV: O += P(16x64) * V(64x128)
        __builtin_amdgcn_s_setprio(1);
#pragma unroll
        for (int kk = 0; kk < 2; ++kk) {
            bf16x8 ap = *(const bf16x8*)(lPw + fr * 128 + swz(fr, kk * 64 + kc * 16));
#pragma unroll
            for (int n8 = 0; n8 < 8; ++n8) {
                int row = n8 * 16 + fr;
                bf16x8 bv = *(const bf16x8*)(lVb + row * 128 + swz(row, kk * 64 + kc * 16));
                o[n8] = __builtin_amdgcn_mfma_f32_16x16x32_bf16(ap, bv, o[n8], 0, 0, 0);
            }
        }
        __builtin_amdgcn_s_setprio(0);
    };

    const int nt = qt + 1;
    stage(0, 0);
    __syncthreads();
    for (int t = 0; t < nt; ++t) {
        if (t + 1 < nt) stage((t + 1) & 1, (t + 1) << 6);
        compute((const char*)lK[t & 1], (const char*)lV[t & 1], t << 6, t == nt - 1);
        __syncthreads();
    }

    // epilogue: y_out[v][t][h*128 + d]; normalize by row-sum (broadcast li)
#pragma unroll
    for (int r = 0; r < 4; ++r) {
        int t = q0 + wsub + kc * 4 + r;
        float lb = __shfl(li_l, kc * 4 + r);
        float inv_l = 1.0f / lb;
#pragma unroll
        for (int n8 = 0; n8 < 8; ++n8)
            y_out[(size_t)v * T_SEQ * DMODEL + (size_t)t * DMODEL + h * 128 + n8 * 16 + fr] =
                o[n8][r] * inv_l;
    }
}

// ---------------- combine y1 - lambda*y2 -> bf16 ----------------
__global__ __launch_bounds__(256) void combine(const float* __restrict__ y,
                                               const float* __restrict__ lamp,
                                               u16* __restrict__ yc) {
    int i = (blockIdx.x * 256 + threadIdx.x) * 4;
    float l = *lamp;
    float4 a = *(const float4*)(y + i);
    float4 b = *(const float4*)(y + 2097152 + i);
    ushort4 o;
    o.x = f2bf(a.x - l * b.x);
    o.y = f2bf(a.y - l * b.y);
    o.z = f2bf(a.z - l * b.z);
    o.w = f2bf(a.w - l * b.w);
    *(ushort4*)(yc + i) = o;
}

extern "C" void kernel_launch(void* const* d_in, const int* in_sizes, int n_in,
                              void* d_out, int out_size, void* d_ws, size_t ws_size,
                              hipStream_t stream) {
    const float* x   = (const float*)d_in[0];
    const float* Wq  = (const float*)d_in[1];
    const float* Wk  = (const float*)d_in[2];
    const float* Wv  = (const float*)d_in[3];
    const float* Wp  = (const float*)d_in[4];
    const float* lq1 = (const float*)d_in[5];
    const float* lk1 = (const float*)d_in[6];
    const float* lq2 = (const float*)d_in[7];
    const float* lk2 = (const float*)d_in[8];
    float* out = (float*)d_out;

    char* ws = (char*)d_ws;
    u16*   x_bf  = (u16*)(ws);                         //  4 MB
    u16*   wq_bf = (u16*)(ws + (4ull << 20));
    u16*   wk_bf = (u16*)(ws + (6ull << 20));
    u16*   wv_bf = (u16*)(ws + (8ull << 20));
    u16*   wp_bf = (u16*)(ws + (10ull << 20));
    u16*   Vbf   = (u16*)(ws + (12ull << 20));         //  4 MB
    u16*   q_bf  = (u16*)(ws + (16ull << 20));         //  4 MB
    u16*   k_bf  = (u16*)(ws + (20ull << 20));         //  4 MB
    u16*   vT_bf = (u16*)(ws + (24ull << 20));         //  4 MB
    float* y12   = (float*)(ws + (28ull << 20));       // 16 MB
    u16*   yc_bf = (u16*)(ws + (44ull << 20));         //  4 MB
    float* cosT  = (float*)(ws + (48ull << 20));
    float* sinT  = (float*)(ws + (48ull << 20) + (256ull << 10));
    float* lam   = (float*)(ws + (48ull << 20) + (512ull << 10));

    prep<<<6401, 256, 0, stream>>>(x, Wq, Wk, Wv, Wp,
                                   x_bf, wq_bf, wk_bf, wv_bf, wp_bf,
                                   cosT, sinT, lq1, lk1, lq2, lk2, lam);

    gemm_qkv<<<dim3(24, 16), 256, 0, stream>>>(x_bf, wq_bf, wk_bf, wv_bf,
                                               cosT, sinT, q_bf, k_bf, Vbf);

    vtrans<<<dim3(32, 64), 256, 0, stream>>>(Vbf, vT_bf);

    attn_kernel<<<dim3(32, 8, 2), 256, 0, stream>>>(q_bf, k_bf, vT_bf, y12);

    combine<<<2048, 256, 0, stream>>>(y12, lam, yc_bf);

    gemm_proj<<<dim3(8, 16), 256, 0, stream>>>(yc_bf, wp_bf, out);
}

// Round 5
// 118.194 us; speedup vs baseline: 2.5706x; 1.1612x over previous
//
#include <hip/hip_runtime.h>
#include <hip/hip_bf16.h>

typedef __attribute__((ext_vector_type(4))) float f32x4;
typedef __attribute__((ext_vector_type(8))) short bf16x8;
typedef unsigned short u16;

#define T_SEQ 2048
#define DMODEL 1024

__device__ __forceinline__ u16 f2bf(float f) {
    __hip_bfloat16 h = __float2bfloat16(f);
    return __builtin_bit_cast(unsigned short, h);
}

typedef const void __attribute__((address_space(1))) gvoid_t;
typedef void __attribute__((address_space(3))) lvoid_t;
__device__ __forceinline__ void gload16(const void* g, void* l) {
    __builtin_amdgcn_global_load_lds((gvoid_t*)g, (lvoid_t*)l, 16, 0, 0);
}

// XOR swizzle for 128B-row LDS tiles (kills 16-way ds_read_b128 conflicts)
__device__ __forceinline__ int swz(int row, int colb) {
    return colb ^ ((row & 7) << 4);
}

// ---------------- fused prep: casts + rope tables + lambda ----------------
__device__ __forceinline__ void cast4(const float* __restrict__ s,
                                      u16* __restrict__ d, int u) {
    int i = u * 4;
    float4 v = *(const float4*)(s + i);
    ushort4 o;
    o.x = f2bf(v.x); o.y = f2bf(v.y); o.z = f2bf(v.z); o.w = f2bf(v.w);
    *(ushort4*)(d + i) = o;
}

__global__ __launch_bounds__(256) void prep(const float* __restrict__ x,
                                            const float* __restrict__ Wq,
                                            const float* __restrict__ Wk,
                                            const float* __restrict__ Wv,
                                            const float* __restrict__ Wp,
                                            u16* __restrict__ x_bf, u16* __restrict__ wq_bf,
                                            u16* __restrict__ wk_bf, u16* __restrict__ wv_bf,
                                            u16* __restrict__ wp_bf,
                                            float* __restrict__ cosT, float* __restrict__ sinT,
                                            const float* __restrict__ lq1, const float* __restrict__ lk1,
                                            const float* __restrict__ lq2, const float* __restrict__ lk2,
                                            float* __restrict__ lam) {
    int b = blockIdx.x;
    if (b < 6144) {
        int u = b * 256 + threadIdx.x;
        if (u < 524288)       cast4(x,  x_bf,  u);
        else if (u < 786432)  cast4(Wq, wq_bf, u - 524288);
        else if (u < 1048576) cast4(Wk, wk_bf, u - 786432);
        else if (u < 1310720) cast4(Wv, wv_bf, u - 1048576);
        else                  cast4(Wp, wp_bf, u - 1310720);
    } else if (b < 6400) {
        int i = (b - 6144) * 256 + threadIdx.x;   // < 2048*32
        int t = i >> 5, j = i & 31;
        float inv = powf(10000.0f, -(float)j * (1.0f / 32.0f));
        float fr = (float)t * inv;
        cosT[i] = cosf(fr);
        sinT[i] = sinf(fr);
    } else if (threadIdx.x == 0) {
        float s1 = 0.f, s2 = 0.f;
        for (int i = 0; i < 32; ++i) { s1 += lq1[i] * lk1[i]; s2 += lq2[i] * lk2[i]; }
        *lam = expf(s1) - expf(s2) + 0.35550906759096928f;
    }
}

// ---------------- GEMM main loop: acc = A[M,K] * B[N,K]^T (64x128 tile) -------
// 4 waves in 2x2, each wave 32 rows x 64 cols, acc[2][4].
__device__ __forceinline__ void gemm_main64(const u16* __restrict__ A,
                                            const u16* __restrict__ B,
                                            int m0, int n0, int K,
                                            u16* lA, u16* lB, f32x4 acc[2][4]) {
    const int tid = threadIdx.x;
    const int lane = tid & 63;
    const int wid = tid >> 6;
    const int wr = (wid >> 1) * 32;
    const int wc = (wid & 1) * 64;
    const int fr = lane & 15;
    const int kc = lane >> 4;
    const char* Ab = (const char*)A;
    const char* Bb = (const char*)B;
    const int rowbytes = K * 2;

    for (int k0 = 0; k0 < K; k0 += 32) {
        {
            int c = tid;   // lA: 64 rows x 32k = 4KB = 256 x 16B
            gload16(Ab + (size_t)(m0 + (c >> 2)) * rowbytes + k0 * 2 + (c & 3) * 16,
                    (char*)lA + c * 16);
        }
#pragma unroll
        for (int i = 0; i < 2; ++i) {
            int c = i * 256 + tid;   // lB: 128 rows x 32k = 8KB
            gload16(Bb + (size_t)(n0 + (c >> 2)) * rowbytes + k0 * 2 + (c & 3) * 16,
                    (char*)lB + c * 16);
        }
        __syncthreads();
        bf16x8 a[2], b[4];
#pragma unroll
        for (int m = 0; m < 2; ++m) a[m] = *(const bf16x8*)&lA[(wr + m * 16 + fr) * 32 + kc * 8];
#pragma unroll
        for (int n = 0; n < 4; ++n) b[n] = *(const bf16x8*)&lB[(wc + n * 16 + fr) * 32 + kc * 8];
#pragma unroll
        for (int m = 0; m < 2; ++m)
#pragma unroll
            for (int n = 0; n < 4; ++n)
                acc[m][n] = __builtin_amdgcn_mfma_f32_16x16x32_bf16(a[m], b[n], acc[m][n], 0, 0, 0);
        __syncthreads();
    }
}

// fused QKV GEMM: grid (24, 32); x-tiles 0-7 -> Q, 8-15 -> K, 16-23 -> V.
// Q/K epilogue: RMS-norm + RoPE fused, writes bf16 planes [p*8+h][t][64].
// V epilogue: cast to bf16 [t][1024].
__global__ __launch_bounds__(256) void gemm_qkv(const u16* __restrict__ A,
                                                const u16* __restrict__ wq,
                                                const u16* __restrict__ wk,
                                                const u16* __restrict__ wv,
                                                const float* __restrict__ cosT,
                                                const float* __restrict__ sinT,
                                                u16* __restrict__ q_bf,
                                                u16* __restrict__ k_bf,
                                                u16* __restrict__ Vbf) {
    __shared__ __align__(16) u16 lA[64 * 32];
    __shared__ __align__(16) u16 lB[128 * 32];
    const int nt = blockIdx.x;
    const int which = nt >> 3;
    const u16* B = (which == 0) ? wq : (which == 1) ? wk : wv;
    const int m0 = blockIdx.y * 64;
    const int n0 = (nt & 7) * 128;

    f32x4 acc[2][4] = {};
    gemm_main64(A, B, m0, n0, 1024, lA, lB, acc);

    const int lane = threadIdx.x & 63;
    const int wid = threadIdx.x >> 6;
    const int wr = (wid >> 1) * 32;
    const int wc = (wid & 1) * 64;
    const int fr = lane & 15;
    const int rr = (lane >> 4) * 4;

    if (which == 2) {
#pragma unroll
        for (int m = 0; m < 2; ++m)
#pragma unroll
            for (int n = 0; n < 4; ++n)
#pragma unroll
                for (int r = 0; r < 4; ++r)
                    Vbf[(size_t)(m0 + wr + m * 16 + rr + r) * 1024 + n0 + wc + n * 16 + fr] =
                        f2bf(acc[m][n][r]);
        return;
    }

    // Q/K: this wave's 64 cols = one (variant p, head h)
    const int cb = n0 + wc;
    const int plane = ((cb >> 9) << 3) | ((cb >> 6) & 7);
    u16* dstp = ((which == 0) ? q_bf : k_bf) + (size_t)plane * T_SEQ * 64;
#pragma unroll
    for (int m = 0; m < 2; ++m)
#pragma unroll
        for (int r = 0; r < 4; ++r) {
            int t = m0 + wr + m * 16 + rr + r;
            float s2 = 0.f;
#pragma unroll
            for (int n = 0; n < 4; ++n) { float a = acc[m][n][r]; s2 += a * a; }
            s2 += __shfl_xor(s2, 1); s2 += __shfl_xor(s2, 2);
            s2 += __shfl_xor(s2, 4); s2 += __shfl_xor(s2, 8);
            float inv = rsqrtf(s2 * (1.0f / 64.0f) + 1.1920929e-7f);
#pragma unroll
            for (int n = 0; n < 4; ++n) {
                float a = acc[m][n][r] * inv;
                float p_ = acc[m][n ^ 2][r] * inv;
                int jj = ((n & 1) << 4) + fr;
                float c = cosT[t * 32 + jj], sn = sinT[t * 32 + jj];
                float ov = (n < 2) ? (a * c + p_ * sn) : (a * c - p_ * sn);
                dstp[(size_t)t * 64 + n * 16 + fr] = f2bf(ov);
            }
        }
}

// grid (8, 32): 64x128 tiles
__global__ __launch_bounds__(256) void gemm_proj(const u16* __restrict__ A,
                                                 const u16* __restrict__ B,
                                                 float* __restrict__ C) {
    __shared__ __align__(16) u16 lA[64 * 32];
    __shared__ __align__(16) u16 lB[128 * 32];
    const int m0 = blockIdx.y * 64;
    const int n0 = blockIdx.x * 128;
    f32x4 acc[2][4] = {};
    gemm_main64(A, B, m0, n0, 1024, lA, lB, acc);
    const int lane = threadIdx.x & 63;
    const int wid = threadIdx.x >> 6;
    const int wr = (wid >> 1) * 32;
    const int wc = (wid & 1) * 64;
    const int fr = lane & 15;
    const int rr = (lane >> 4) * 4;
#pragma unroll
    for (int m = 0; m < 2; ++m)
#pragma unroll
        for (int n = 0; n < 4; ++n)
#pragma unroll
            for (int r = 0; r < 4; ++r)
                C[(size_t)(m0 + wr + m * 16 + rr + r) * 1024 + (n0 + wc + n * 16 + fr)] =
                    acc[m][n][r];
}

// ---------------- V transpose (bf16): Vbf[t][1024] -> vT[h*128+d][t] ----------
__global__ __launch_bounds__(256) void vtrans(const u16* __restrict__ Vbf,
                                              u16* __restrict__ vT) {
    __shared__ u16 tile[32][34];
    int tx = threadIdx.x & 31;
    int ty = threadIdx.x >> 5;
    int c0 = blockIdx.x * 32;
    int r0 = blockIdx.y * 32;
#pragma unroll
    for (int i = ty; i < 32; i += 8)
        tile[i][tx] = Vbf[(size_t)(r0 + i) * 1024 + c0 + tx];
    __syncthreads();
#pragma unroll
    for (int i = ty; i < 32; i += 8)
        vT[(size_t)(c0 + i) * T_SEQ + r0 + tx] = tile[tx][i];
}

// ---------------- flash attention (causal, QBLK=64, KV tile 64) --------------
// grid (32, 8, 2). qt complementary across variants so each CU's two resident
// blocks sum to 33 KV-tiles (load balance). Swapped QK^T: lane-local softmax.
__global__ __launch_bounds__(256) void attn_kernel(const u16* __restrict__ q_bf,
                                                   const u16* __restrict__ k_bf,
                                                   const u16* __restrict__ vT_bf,
                                                   float* __restrict__ y_out) {
    __shared__ __align__(16) u16 lK[2][64 * 64];
    __shared__ __align__(16) u16 lV[2][128 * 64];
    __shared__ __align__(16) u16 lP[4][16 * 64];

    const int tid = threadIdx.x, lane = tid & 63, wid = tid >> 6;
    const int idx = blockIdx.x, h = blockIdx.y, v = blockIdx.z;
    const int pr = (idx & 1) ? (31 - (idx >> 1)) : (idx >> 1);
    const int qt = v ? (31 - pr) : pr;   // complementary across variants
    const int q0 = qt * 64;
    const int plane = v * 8 + h;
    const u16* qp = q_bf + (size_t)plane * T_SEQ * 64;
    const char* kp = (const char*)(k_bf + (size_t)plane * T_SEQ * 64);
    const char* vp = (const char*)(vT_bf + (size_t)h * 128 * T_SEQ);
    const int fr = lane & 15, kc = lane >> 4;
    const int wsub = wid * 16;
    char* lPw = (char*)lP[wid];

    // Q fragments held in registers for the whole kernel (B-operand of K·Q^T)
    bf16x8 aq[2];
#pragma unroll
    for (int kq = 0; kq < 2; ++kq)
        aq[kq] = *(const bf16x8*)(qp + (size_t)(q0 + wsub + fr) * 64 + kq * 32 + kc * 8);

    f32x4 o[8] = {};
    float mi_l = -1e30f, li_l = 0.f;   // per-lane: q-row = q0+wsub+fr

    const float SL = 0.125f * 1.4426950408889634f;   // scale * log2(e)
    const int qrow = q0 + wsub + fr;

    auto stage = [&](int b, int s0) {
#pragma unroll
        for (int i = 0; i < 2; ++i) {
            int c = i * 256 + tid;
            int row = c >> 3, cp = (c & 7) * 16;
            gload16(kp + (size_t)(s0 + row) * 128 + swz(row, cp), (char*)lK[b] + c * 16);
        }
#pragma unroll
        for (int i = 0; i < 4; ++i) {
            int c = i * 256 + tid;
            int row = c >> 3, cp = (c & 7) * 16;
            gload16(vp + (size_t)row * (T_SEQ * 2) + (size_t)s0 * 2 + swz(row, cp),
                    (char*)lV[b] + c * 16);
        }
    };

    auto compute = [&](const char* lKb, const char* lVb, int s0, bool diag) {
        // S^T: A = K rows, B = Q rows. sacc[n][r] = S[s0+n*16+kc*4+r][qrow]
        f32x4 sacc[4] = {};
        __builtin_amdgcn_s_setprio(1);
#pragma unroll
        for (int kq = 0; kq < 2; ++kq)
#pragma unroll
            for (int n = 0; n < 4; ++n) {
                int row = n * 16 + fr;
                bf16x8 bk = *(const bf16x8*)(lKb + row * 128 + swz(row, kq * 64 + kc * 16));
                sacc[n] = __builtin_amdgcn_mfma_f32_16x16x32_bf16(bk, aq[kq], sacc[n], 0, 0, 0);
            }
        __builtin_amdgcn_s_setprio(0);

        // scale (+ mask only on diag tile), lane-local max
#pragma unroll
        for (int n = 0; n < 4; ++n)
#pragma unroll
            for (int r = 0; r < 4; ++r)
                sacc[n][r] *= SL;
        if (diag) {
#pragma unroll
            for (int n = 0; n < 4; ++n)
#pragma unroll
                for (int r = 0; r < 4; ++r)
                    if (s0 + n * 16 + kc * 4 + r > qrow) sacc[n][r] = -1e30f;
        }
        float rmax = -1e30f;
#pragma unroll
        for (int n = 0; n < 4; ++n)
#pragma unroll
            for (int r = 0; r < 4; ++r)
                rmax = fmaxf(rmax, sacc[n][r]);
        rmax = fmaxf(rmax, __shfl_xor(rmax, 16));
        rmax = fmaxf(rmax, __shfl_xor(rmax, 32));

        // T13 defer-max: only raise m when it grows by > 8 (exp2 domain)
        bool raise = rmax > mi_l + 8.0f;
        float f = raise ? __builtin_exp2f(mi_l - rmax) : 1.0f;
        if (raise) mi_l = rmax;

        float rs = 0.f;
#pragma unroll
        for (int n = 0; n < 4; ++n)
#pragma unroll
            for (int r = 0; r < 4; ++r) {
                float p = __builtin_exp2f(sacc[n][r] - mi_l);
                sacc[n][r] = p;
                rs += p;
            }
        rs += __shfl_xor(rs, 16);
        rs += __shfl_xor(rs, 32);
        li_l = li_l * f + rs;

        if (__any(raise)) {
#pragma unroll
            for (int r = 0; r < 4; ++r) {
                float fb = __shfl(f, kc * 4 + r);
#pragma unroll
                for (int n8 = 0; n8 < 8; ++n8) o[n8][r] *= fb;
            }
        }

        // P -> LDS: row q=fr, 4 k-consecutive bf16 per write (b64), swizzled
#pragma unroll
        for (int n = 0; n < 4; ++n) {
            ushort4 pk;
            pk.x = f2bf(sacc[n][0]); pk.y = f2bf(sacc[n][1]);
            pk.z = f2bf(sacc[n][2]); pk.w = f2bf(sacc[n][3]);
            *(ushort4*)(lPw + fr * 128 + ((n * 32 + kc * 8) ^ ((fr & 7) << 4))) = pk;
        }

        // PV: O += P(16x64) * V(64x128)
        __builtin_amdgcn_s_setprio(1);
#pragma unroll
        for (int kk = 0; kk < 2; ++kk) {
            bf16x8 ap = *(const bf16x8*)(lPw + fr * 128 + swz(fr, kk * 64 + kc * 16));
#pragma unroll
            for (int n8 = 0; n8 < 8; ++n8) {
                int row = n8 * 16 + fr;
                bf16x8 bv = *(const bf16x8*)(lVb + row * 128 + swz(row, kk * 64 + kc * 16));
                o[n8] = __builtin_amdgcn_mfma_f32_16x16x32_bf16(ap, bv, o[n8], 0, 0, 0);
            }
        }
        __builtin_amdgcn_s_setprio(0);
    };

    const int nt = qt + 1;
    stage(0, 0);
    __syncthreads();
    for (int t = 0; t < nt; ++t) {
        if (t + 1 < nt) stage((t + 1) & 1, (t + 1) << 6);
        compute((const char*)lK[t & 1], (const char*)lV[t & 1], t << 6, t == nt - 1);
        __syncthreads();
    }

    // epilogue: y_out[v][t][h*128 + d]; normalize by row-sum (broadcast li)
#pragma unroll
    for (int r = 0; r < 4; ++r) {
        int t = q0 + wsub + kc * 4 + r;
        float lb = __shfl(li_l, kc * 4 + r);
        float inv_l = 1.0f / lb;
#pragma unroll
        for (int n8 = 0; n8 < 8; ++n8)
            y_out[(size_t)v * T_SEQ * DMODEL + (size_t)t * DMODEL + h * 128 + n8 * 16 + fr] =
                o[n8][r] * inv_l;
    }
}

// ---------------- combine y1 - lambda*y2 -> bf16 ----------------
__global__ __launch_bounds__(256) void combine(const float* __restrict__ y,
                                               const float* __restrict__ lamp,
                                               u16* __restrict__ yc) {
    int i = (blockIdx.x * 256 + threadIdx.x) * 4;
    float l = *lamp;
    float4 a = *(const float4*)(y + i);
    float4 b = *(const float4*)(y + 2097152 + i);
    ushort4 o;
    o.x = f2bf(a.x - l * b.x);
    o.y = f2bf(a.y - l * b.y);
    o.z = f2bf(a.z - l * b.z);
    o.w = f2bf(a.w - l * b.w);
    *(ushort4*)(yc + i) = o;
}

extern "C" void kernel_launch(void* const* d_in, const int* in_sizes, int n_in,
                              void* d_out, int out_size, void* d_ws, size_t ws_size,
                              hipStream_t stream) {
    const float* x   = (const float*)d_in[0];
    const float* Wq  = (const float*)d_in[1];
    const float* Wk  = (const float*)d_in[2];
    const float* Wv  = (const float*)d_in[3];
    const float* Wp  = (const float*)d_in[4];
    const float* lq1 = (const float*)d_in[5];
    const float* lk1 = (const float*)d_in[6];
    const float* lq2 = (const float*)d_in[7];
    const float* lk2 = (const float*)d_in[8];
    float* out = (float*)d_out;

    char* ws = (char*)d_ws;
    u16*   x_bf  = (u16*)(ws);                         //  4 MB
    u16*   wq_bf = (u16*)(ws + (4ull << 20));
    u16*   wk_bf = (u16*)(ws + (6ull << 20));
    u16*   wv_bf = (u16*)(ws + (8ull << 20));
    u16*   wp_bf = (u16*)(ws + (10ull << 20));
    u16*   Vbf   = (u16*)(ws + (12ull << 20));         //  4 MB
    u16*   q_bf  = (u16*)(ws + (16ull << 20));         //  4 MB
    u16*   k_bf  = (u16*)(ws + (20ull << 20));         //  4 MB
    u16*   vT_bf = (u16*)(ws + (24ull << 20));         //  4 MB
    float* y12   = (float*)(ws + (28ull << 20));       // 16 MB
    u16*   yc_bf = (u16*)(ws + (44ull << 20));         //  4 MB
    float* cosT  = (float*)(ws + (48ull << 20));
    float* sinT  = (float*)(ws + (48ull << 20) + (256ull << 10));
    float* lam   = (float*)(ws + (48ull << 20) + (512ull << 10));

    prep<<<6401, 256, 0, stream>>>(x, Wq, Wk, Wv, Wp,
                                   x_bf, wq_bf, wk_bf, wv_bf, wp_bf,
                                   cosT, sinT, lq1, lk1, lq2, lk2, lam);

    gemm_qkv<<<dim3(24, 32), 256, 0, stream>>>(x_bf, wq_bf, wk_bf, wv_bf,
                                               cosT, sinT, q_bf, k_bf, Vbf);

    vtrans<<<dim3(32, 64), 256, 0, stream>>>(Vbf, vT_bf);

    attn_kernel<<<dim3(32, 8, 2), 256, 0, stream>>>(q_bf, k_bf, vT_bf, y12);

    combine<<<2048, 256, 0, stream>>>(y12, lam, yc_bf);

    gemm_proj<<<dim3(8, 32), 256, 0, stream>>>(yc_bf, wp_bf, out);
}

// Round 6
// 118.034 us; speedup vs baseline: 2.5741x; 1.0014x over previous
//
#include <hip/hip_runtime.h>
#include <hip/hip_bf16.h>

typedef __attribute__((ext_vector_type(4))) float f32x4;
typedef __attribute__((ext_vector_type(8))) short bf16x8;
typedef unsigned short u16;

#define T_SEQ 2048
#define DMODEL 1024

__device__ __forceinline__ u16 f2bf(float f) {
    __hip_bfloat16 h = __float2bfloat16(f);
    return __builtin_bit_cast(unsigned short, h);
}

typedef const void __attribute__((address_space(1))) gvoid_t;
typedef void __attribute__((address_space(3))) lvoid_t;
__device__ __forceinline__ void gload16(const void* g, void* l) {
    __builtin_amdgcn_global_load_lds((gvoid_t*)g, (lvoid_t*)l, 16, 0, 0);
}

// XOR swizzle for 128B-row LDS tiles (kills 16-way ds_read_b128 conflicts)
__device__ __forceinline__ int swz(int row, int colb) {
    return colb ^ ((row & 7) << 4);
}

// ---------------- fused prep: casts + rope tables + lambda ----------------
__device__ __forceinline__ void cast4(const float* __restrict__ s,
                                      u16* __restrict__ d, int u) {
    int i = u * 4;
    float4 v = *(const float4*)(s + i);
    ushort4 o;
    o.x = f2bf(v.x); o.y = f2bf(v.y); o.z = f2bf(v.z); o.w = f2bf(v.w);
    *(ushort4*)(d + i) = o;
}

__global__ __launch_bounds__(256) void prep(const float* __restrict__ x,
                                            const float* __restrict__ Wq,
                                            const float* __restrict__ Wk,
                                            const float* __restrict__ Wv,
                                            const float* __restrict__ Wp,
                                            u16* __restrict__ x_bf, u16* __restrict__ wq_bf,
                                            u16* __restrict__ wk_bf, u16* __restrict__ wv_bf,
                                            u16* __restrict__ wp_bf,
                                            float* __restrict__ cosT, float* __restrict__ sinT,
                                            const float* __restrict__ lq1, const float* __restrict__ lk1,
                                            const float* __restrict__ lq2, const float* __restrict__ lk2,
                                            float* __restrict__ lam) {
    int b = blockIdx.x;
    if (b < 6144) {
        int u = b * 256 + threadIdx.x;
        if (u < 524288)       cast4(x,  x_bf,  u);
        else if (u < 786432)  cast4(Wq, wq_bf, u - 524288);
        else if (u < 1048576) cast4(Wk, wk_bf, u - 786432);
        else if (u < 1310720) cast4(Wv, wv_bf, u - 1048576);
        else                  cast4(Wp, wp_bf, u - 1310720);
    } else if (b < 6400) {
        int i = (b - 6144) * 256 + threadIdx.x;   // < 2048*32
        int t = i >> 5, j = i & 31;
        float inv = powf(10000.0f, -(float)j * (1.0f / 32.0f));
        float fr = (float)t * inv;
        cosT[i] = cosf(fr);
        sinT[i] = sinf(fr);
    } else if (threadIdx.x == 0) {
        float s1 = 0.f, s2 = 0.f;
        for (int i = 0; i < 32; ++i) { s1 += lq1[i] * lk1[i]; s2 += lq2[i] * lk2[i]; }
        *lam = expf(s1) - expf(s2) + 0.35550906759096928f;
    }
}

// ---------------- GEMM main loop: acc = A[M,K] * B[N,K]^T (64x128 tile) -------
// 4 waves in 2x2, each wave 32 rows x 64 cols, acc[2][4].
__device__ __forceinline__ void gemm_main64(const u16* __restrict__ A,
                                            const u16* __restrict__ B,
                                            int m0, int n0, int K,
                                            u16* lA, u16* lB, f32x4 acc[2][4]) {
    const int tid = threadIdx.x;
    const int lane = tid & 63;
    const int wid = tid >> 6;
    const int wr = (wid >> 1) * 32;
    const int wc = (wid & 1) * 64;
    const int fr = lane & 15;
    const int kc = lane >> 4;
    const char* Ab = (const char*)A;
    const char* Bb = (const char*)B;
    const int rowbytes = K * 2;

    for (int k0 = 0; k0 < K; k0 += 32) {
        {
            int c = tid;   // lA: 64 rows x 32k = 4KB = 256 x 16B
            gload16(Ab + (size_t)(m0 + (c >> 2)) * rowbytes + k0 * 2 + (c & 3) * 16,
                    (char*)lA + c * 16);
        }
#pragma unroll
        for (int i = 0; i < 2; ++i) {
            int c = i * 256 + tid;   // lB: 128 rows x 32k = 8KB
            gload16(Bb + (size_t)(n0 + (c >> 2)) * rowbytes + k0 * 2 + (c & 3) * 16,
                    (char*)lB + c * 16);
        }
        __syncthreads();
        bf16x8 a[2], b[4];
#pragma unroll
        for (int m = 0; m < 2; ++m) a[m] = *(const bf16x8*)&lA[(wr + m * 16 + fr) * 32 + kc * 8];
#pragma unroll
        for (int n = 0; n < 4; ++n) b[n] = *(const bf16x8*)&lB[(wc + n * 16 + fr) * 32 + kc * 8];
#pragma unroll
        for (int m = 0; m < 2; ++m)
#pragma unroll
            for (int n = 0; n < 4; ++n)
                acc[m][n] = __builtin_amdgcn_mfma_f32_16x16x32_bf16(a[m], b[n], acc[m][n], 0, 0, 0);
        __syncthreads();
    }
}

// fused QKV GEMM: grid (24, 32); x-tiles 0-7 -> Q, 8-15 -> K, 16-23 -> V.
// Q/K epilogue: RMS-norm + RoPE fused, writes bf16 planes [p*8+h][t][64].
// V epilogue: cast to bf16 [t][1024].
__global__ __launch_bounds__(256) void gemm_qkv(const u16* __restrict__ A,
                                                const u16* __restrict__ wq,
                                                const u16* __restrict__ wk,
                                                const u16* __restrict__ wv,
                                                const float* __restrict__ cosT,
                                                const float* __restrict__ sinT,
                                                u16* __restrict__ q_bf,
                                                u16* __restrict__ k_bf,
                                                u16* __restrict__ Vbf) {
    __shared__ __align__(16) u16 lA[64 * 32];
    __shared__ __align__(16) u16 lB[128 * 32];
    const int nt = blockIdx.x;
    const int which = nt >> 3;
    const u16* B = (which == 0) ? wq : (which == 1) ? wk : wv;
    const int m0 = blockIdx.y * 64;
    const int n0 = (nt & 7) * 128;

    f32x4 acc[2][4] = {};
    gemm_main64(A, B, m0, n0, 1024, lA, lB, acc);

    const int lane = threadIdx.x & 63;
    const int wid = threadIdx.x >> 6;
    const int wr = (wid >> 1) * 32;
    const int wc = (wid & 1) * 64;
    const int fr = lane & 15;
    const int rr = (lane >> 4) * 4;

    if (which == 2) {
#pragma unroll
        for (int m = 0; m < 2; ++m)
#pragma unroll
            for (int n = 0; n < 4; ++n)
#pragma unroll
                for (int r = 0; r < 4; ++r)
                    Vbf[(size_t)(m0 + wr + m * 16 + rr + r) * 1024 + n0 + wc + n * 16 + fr] =
                        f2bf(acc[m][n][r]);
        return;
    }

    // Q/K: this wave's 64 cols = one (variant p, head h)
    const int cb = n0 + wc;
    const int plane = ((cb >> 9) << 3) | ((cb >> 6) & 7);
    u16* dstp = ((which == 0) ? q_bf : k_bf) + (size_t)plane * T_SEQ * 64;
#pragma unroll
    for (int m = 0; m < 2; ++m)
#pragma unroll
        for (int r = 0; r < 4; ++r) {
            int t = m0 + wr + m * 16 + rr + r;
            float s2 = 0.f;
#pragma unroll
            for (int n = 0; n < 4; ++n) { float a = acc[m][n][r]; s2 += a * a; }
            s2 += __shfl_xor(s2, 1); s2 += __shfl_xor(s2, 2);
            s2 += __shfl_xor(s2, 4); s2 += __shfl_xor(s2, 8);
            float inv = rsqrtf(s2 * (1.0f / 64.0f) + 1.1920929e-7f);
#pragma unroll
            for (int n = 0; n < 4; ++n) {
                float a = acc[m][n][r] * inv;
                float p_ = acc[m][n ^ 2][r] * inv;
                int jj = ((n & 1) << 4) + fr;
                float c = cosT[t * 32 + jj], sn = sinT[t * 32 + jj];
                float ov = (n < 2) ? (a * c + p_ * sn) : (a * c - p_ * sn);
                dstp[(size_t)t * 64 + n * 16 + fr] = f2bf(ov);
            }
        }
}

// grid (8, 32): 64x128 tiles
__global__ __launch_bounds__(256) void gemm_proj(const u16* __restrict__ A,
                                                 const u16* __restrict__ B,
                                                 float* __restrict__ C) {
    __shared__ __align__(16) u16 lA[64 * 32];
    __shared__ __align__(16) u16 lB[128 * 32];
    const int m0 = blockIdx.y * 64;
    const int n0 = blockIdx.x * 128;
    f32x4 acc[2][4] = {};
    gemm_main64(A, B, m0, n0, 1024, lA, lB, acc);
    const int lane = threadIdx.x & 63;
    const int wid = threadIdx.x >> 6;
    const int wr = (wid >> 1) * 32;
    const int wc = (wid & 1) * 64;
    const int fr = lane & 15;
    const int rr = (lane >> 4) * 4;
#pragma unroll
    for (int m = 0; m < 2; ++m)
#pragma unroll
        for (int n = 0; n < 4; ++n)
#pragma unroll
            for (int r = 0; r < 4; ++r)
                C[(size_t)(m0 + wr + m * 16 + rr + r) * 1024 + (n0 + wc + n * 16 + fr)] =
                    acc[m][n][r];
}

// ---------------- V transpose (bf16): Vbf[t][1024] -> vT[h*128+d][t] ----------
__global__ __launch_bounds__(256) void vtrans(const u16* __restrict__ Vbf,
                                              u16* __restrict__ vT) {
    __shared__ u16 tile[32][34];
    int tx = threadIdx.x & 31;
    int ty = threadIdx.x >> 5;
    int c0 = blockIdx.x * 32;
    int r0 = blockIdx.y * 32;
#pragma unroll
    for (int i = ty; i < 32; i += 8)
        tile[i][tx] = Vbf[(size_t)(r0 + i) * 1024 + c0 + tx];
    __syncthreads();
#pragma unroll
    for (int i = ty; i < 32; i += 8)
        vT[(size_t)(c0 + i) * T_SEQ + r0 + tx] = tile[tx][i];
}

// ---------------- flash attention (causal, QBLK=64, KV tile 64) --------------
// grid (32, 8, 2). qt complementary across variants (CU load balance).
// Swapped QK^T AND swapped PV: q-row = lane fr everywhere (m, l, O all
// lane-local). Triple-buffered K/V staging with counted vmcnt (T4).
__global__ __launch_bounds__(256) void attn_kernel(const u16* __restrict__ q_bf,
                                                   const u16* __restrict__ k_bf,
                                                   const u16* __restrict__ vT_bf,
                                                   float* __restrict__ y_out) {
    __shared__ __align__(16) u16 lK[3][64 * 64];
    __shared__ __align__(16) u16 lV[3][128 * 64];
    __shared__ __align__(16) u16 lP[4][16 * 64];

    const int tid = threadIdx.x, lane = tid & 63, wid = tid >> 6;
    const int idx = blockIdx.x, h = blockIdx.y, v = blockIdx.z;
    const int pr = (idx & 1) ? (31 - (idx >> 1)) : (idx >> 1);
    const int qt = v ? (31 - pr) : pr;   // complementary across variants
    const int q0 = qt * 64;
    const int plane = v * 8 + h;
    const u16* qp = q_bf + (size_t)plane * T_SEQ * 64;
    const char* kp = (const char*)(k_bf + (size_t)plane * T_SEQ * 64);
    const char* vp = (const char*)(vT_bf + (size_t)h * 128 * T_SEQ);
    const int fr = lane & 15, kc = lane >> 4;
    const int wsub = wid * 16;
    char* lPw = (char*)lP[wid];

    // Q fragments held in registers for the whole kernel (B-operand of K·Q^T)
    bf16x8 aq[2];
#pragma unroll
    for (int kq = 0; kq < 2; ++kq)
        aq[kq] = *(const bf16x8*)(qp + (size_t)(q0 + wsub + fr) * 64 + kq * 32 + kc * 8);

    f32x4 o[8] = {};                    // O^T: o[n8][r] = O[q=fr][d=n8*16+kc*4+r]
    float mi_l = -1e30f, li_l = 0.f;    // per-lane, q-row = q0+wsub+fr

    const float SL = 0.125f * 1.4426950408889634f;   // scale * log2(e)
    const int qrow = q0 + wsub + fr;

    auto stage = [&](int b, int s0) {
#pragma unroll
        for (int i = 0; i < 2; ++i) {
            int c = i * 256 + tid;
            int row = c >> 3, cp = (c & 7) * 16;
            gload16(kp + (size_t)(s0 + row) * 128 + swz(row, cp), (char*)lK[b] + c * 16);
        }
#pragma unroll
        for (int i = 0; i < 4; ++i) {
            int c = i * 256 + tid;
            int row = c >> 3, cp = (c & 7) * 16;
            gload16(vp + (size_t)row * (T_SEQ * 2) + (size_t)s0 * 2 + swz(row, cp),
                    (char*)lV[b] + c * 16);
        }
    };

    auto compute = [&](const char* lKb, const char* lVb, int s0, bool diag) {
        // S^T: A = K rows, B = Q rows. sacc[n][r] = S[q=fr][k=s0+n*16+kc*4+r]
        f32x4 sacc[4] = {};
        __builtin_amdgcn_s_setprio(1);
#pragma unroll
        for (int kq = 0; kq < 2; ++kq)
#pragma unroll
            for (int n = 0; n < 4; ++n) {
                int row = n * 16 + fr;
                bf16x8 bk = *(const bf16x8*)(lKb + row * 128 + swz(row, kq * 64 + kc * 16));
                sacc[n] = __builtin_amdgcn_mfma_f32_16x16x32_bf16(bk, aq[kq], sacc[n], 0, 0, 0);
            }
        __builtin_amdgcn_s_setprio(0);

        // scale (+ mask only on diag tile), lane-local max
#pragma unroll
        for (int n = 0; n < 4; ++n)
#pragma unroll
            for (int r = 0; r < 4; ++r)
                sacc[n][r] *= SL;
        if (diag) {
#pragma unroll
            for (int n = 0; n < 4; ++n)
#pragma unroll
                for (int r = 0; r < 4; ++r)
                    if (s0 + n * 16 + kc * 4 + r > qrow) sacc[n][r] = -1e30f;
        }
        float rmax = -1e30f;
#pragma unroll
        for (int n = 0; n < 4; ++n)
#pragma unroll
            for (int r = 0; r < 4; ++r)
                rmax = fmaxf(rmax, sacc[n][r]);
        rmax = fmaxf(rmax, __shfl_xor(rmax, 16));
        rmax = fmaxf(rmax, __shfl_xor(rmax, 32));

        // T13 defer-max: only raise m when it grows by > 8 (exp2 domain)
        bool raise = rmax > mi_l + 8.0f;
        float f = raise ? __builtin_exp2f(mi_l - rmax) : 1.0f;
        if (raise) mi_l = rmax;

        float rs = 0.f;
#pragma unroll
        for (int n = 0; n < 4; ++n)
#pragma unroll
            for (int r = 0; r < 4; ++r) {
                float p = __builtin_exp2f(sacc[n][r] - mi_l);
                sacc[n][r] = p;
                rs += p;
            }
        rs += __shfl_xor(rs, 16);
        rs += __shfl_xor(rs, 32);
        li_l = li_l * f + rs;

        if (__any(raise)) {   // O rescale is fully lane-local now
#pragma unroll
            for (int n8 = 0; n8 < 8; ++n8)
#pragma unroll
                for (int r = 0; r < 4; ++r) o[n8][r] *= f;
        }

        // P -> LDS: row q=fr, 4 k-consecutive bf16 per write (b64), swizzled
#pragma unroll
        for (int n = 0; n < 4; ++n) {
            ushort4 pk;
            pk.x = f2bf(sacc[n][0]); pk.y = f2bf(sacc[n][1]);
            pk.z = f2bf(sacc[n][2]); pk.w = f2bf(sacc[n][3]);
            *(ushort4*)(lPw + fr * 128 + ((n * 32 + kc * 8) ^ ((fr & 7) << 4))) = pk;
        }

        // PV swapped: O^T += V^T(16x32 rows d) x P(rows q) -> col = q = fr
        __builtin_amdgcn_s_setprio(1);
#pragma unroll
        for (int kk = 0; kk < 2; ++kk) {
            bf16x8 ap = *(const bf16x8*)(lPw + fr * 128 + swz(fr, kk * 64 + kc * 16));
#pragma unroll
            for (int n8 = 0; n8 < 8; ++n8) {
                int row = n8 * 16 + fr;
                bf16x8 bv = *(const bf16x8*)(lVb + row * 128 + swz(row, kk * 64 + kc * 16));
                o[n8] = __builtin_amdgcn_mfma_f32_16x16x32_bf16(bv, ap, o[n8], 0, 0, 0);
            }
        }
        __builtin_amdgcn_s_setprio(0);
    };

    const int nt = qt + 1;
    stage(0, 0);
    if (nt > 1) stage(1, 64);
    int cur = 0, nxt = 2;
    for (int t = 0; t < nt; ++t) {
        if (t + 2 < nt) {
            stage(nxt, (t + 2) << 6);
            asm volatile("s_waitcnt vmcnt(12)" ::: "memory");
        } else if (t + 1 < nt) {
            asm volatile("s_waitcnt vmcnt(6)" ::: "memory");
        } else {
            asm volatile("s_waitcnt vmcnt(0)" ::: "memory");
        }
        __builtin_amdgcn_sched_barrier(0);
        __builtin_amdgcn_s_barrier();       // all waves: stage(t) complete
        __builtin_amdgcn_sched_barrier(0);
        compute((const char*)lK[cur], (const char*)lV[cur], t << 6, t == nt - 1);
        __builtin_amdgcn_s_barrier();       // compute(t) reads done before overwrite
        cur = (cur == 2) ? 0 : cur + 1;
        nxt = (nxt == 2) ? 0 : nxt + 1;
    }

    // epilogue: O^T -> y_out[v][t=q0+wsub+fr][h*128 + n8*16 + kc*4 + r], float4
    const float inv_l = 1.0f / li_l;
    float* yb = y_out + (size_t)v * T_SEQ * DMODEL + (size_t)qrow * DMODEL + h * 128 + kc * 4;
#pragma unroll
    for (int n8 = 0; n8 < 8; ++n8) {
        float4 w;
        w.x = o[n8][0] * inv_l;
        w.y = o[n8][1] * inv_l;
        w.z = o[n8][2] * inv_l;
        w.w = o[n8][3] * inv_l;
        *(float4*)(yb + n8 * 16) = w;
    }
}

// ---------------- combine y1 - lambda*y2 -> bf16 ----------------
__global__ __launch_bounds__(256) void combine(const float* __restrict__ y,
                                               const float* __restrict__ lamp,
                                               u16* __restrict__ yc) {
    int i = (blockIdx.x * 256 + threadIdx.x) * 4;
    float l = *lamp;
    float4 a = *(const float4*)(y + i);
    float4 b = *(const float4*)(y + 2097152 + i);
    ushort4 o;
    o.x = f2bf(a.x - l * b.x);
    o.y = f2bf(a.y - l * b.y);
    o.z = f2bf(a.z - l * b.z);
    o.w = f2bf(a.w - l * b.w);
    *(ushort4*)(yc + i) = o;
}

extern "C" void kernel_launch(void* const* d_in, const int* in_sizes, int n_in,
                              void* d_out, int out_size, void* d_ws, size_t ws_size,
                              hipStream_t stream) {
    const float* x   = (const float*)d_in[0];
    const float* Wq  = (const float*)d_in[1];
    const float* Wk  = (const float*)d_in[2];
    const float* Wv  = (const float*)d_in[3];
    const float* Wp  = (const float*)d_in[4];
    const float* lq1 = (const float*)d_in[5];
    const float* lk1 = (const float*)d_in[6];
    const float* lq2 = (const float*)d_in[7];
    const float* lk2 = (const float*)d_in[8];
    float* out = (float*)d_out;

    char* ws = (char*)d_ws;
    u16*   x_bf  = (u16*)(ws);                         //  4 MB
    u16*   wq_bf = (u16*)(ws + (4ull << 20));
    u16*   wk_bf = (u16*)(ws + (6ull << 20));
    u16*   wv_bf = (u16*)(ws + (8ull << 20));
    u16*   wp_bf = (u16*)(ws + (10ull << 20));
    u16*   Vbf   = (u16*)(ws + (12ull << 20));         //  4 MB
    u16*   q_bf  = (u16*)(ws + (16ull << 20));         //  4 MB
    u16*   k_bf  = (u16*)(ws + (20ull << 20));         //  4 MB
    u16*   vT_bf = (u16*)(ws + (24ull << 20));         //  4 MB
    float* y12   = (float*)(ws + (28ull << 20));       // 16 MB
    u16*   yc_bf = (u16*)(ws + (44ull << 20));         //  4 MB
    float* cosT  = (float*)(ws + (48ull << 20));
    float* sinT  = (float*)(ws + (48ull << 20) + (256ull << 10));
    float* lam   = (float*)(ws + (48ull << 20) + (512ull << 10));

    prep<<<6401, 256, 0, stream>>>(x, Wq, Wk, Wv, Wp,
                                   x_bf, wq_bf, wk_bf, wv_bf, wp_bf,
                                   cosT, sinT, lq1, lk1, lq2, lk2, lam);

    gemm_qkv<<<dim3(24, 32), 256, 0, stream>>>(x_bf, wq_bf, wk_bf, wv_bf,
                                               cosT, sinT, q_bf, k_bf, Vbf);

    vtrans<<<dim3(32, 64), 256, 0, stream>>>(Vbf, vT_bf);

    attn_kernel<<<dim3(32, 8, 2), 256, 0, stream>>>(q_bf, k_bf, vT_bf, y12);

    combine<<<2048, 256, 0, stream>>>(y12, lam, yc_bf);

    gemm_proj<<<dim3(8, 32), 256, 0, stream>>>(yc_bf, wp_bf, out);
}

// Round 7
// 112.112 us; speedup vs baseline: 2.7100x; 1.0528x over previous
//
#include <hip/hip_runtime.h>
#include <hip/hip_bf16.h>

typedef __attribute__((ext_vector_type(4))) float f32x4;
typedef __attribute__((ext_vector_type(8))) short bf16x8;
typedef unsigned short u16;

#define T_SEQ 2048
#define DMODEL 1024

__device__ __forceinline__ u16 f2bf(float f) {
    __hip_bfloat16 h = __float2bfloat16(f);
    return __builtin_bit_cast(unsigned short, h);
}
__device__ __forceinline__ u16 f2h(float f) {
    _Float16 h = (_Float16)f;
    return __builtin_bit_cast(unsigned short, h);
}
__device__ __forceinline__ float h2f(u16 b) {
    return (float)__builtin_bit_cast(_Float16, b);
}

typedef const void __attribute__((address_space(1))) gvoid_t;
typedef void __attribute__((address_space(3))) lvoid_t;
__device__ __forceinline__ void gload16(const void* g, void* l) {
    __builtin_amdgcn_global_load_lds((gvoid_t*)g, (lvoid_t*)l, 16, 0, 0);
}

// XOR swizzle for 128B-row LDS tiles (kills 16-way ds_read_b128 conflicts)
__device__ __forceinline__ int swz(int row, int colb) {
    return colb ^ ((row & 7) << 4);
}

// ---------------- fused prep: casts + rope tables + lambda ----------------
__device__ __forceinline__ void cast4(const float* __restrict__ s,
                                      u16* __restrict__ d, int u) {
    int i = u * 4;
    float4 v = *(const float4*)(s + i);
    ushort4 o;
    o.x = f2bf(v.x); o.y = f2bf(v.y); o.z = f2bf(v.z); o.w = f2bf(v.w);
    *(ushort4*)(d + i) = o;
}

__global__ __launch_bounds__(256) void prep(const float* __restrict__ x,
                                            const float* __restrict__ Wq,
                                            const float* __restrict__ Wk,
                                            const float* __restrict__ Wv,
                                            const float* __restrict__ Wp,
                                            u16* __restrict__ x_bf, u16* __restrict__ wq_bf,
                                            u16* __restrict__ wk_bf, u16* __restrict__ wv_bf,
                                            u16* __restrict__ wp_bf,
                                            float* __restrict__ cosT, float* __restrict__ sinT,
                                            const float* __restrict__ lq1, const float* __restrict__ lk1,
                                            const float* __restrict__ lq2, const float* __restrict__ lk2,
                                            float* __restrict__ lam) {
    int b = blockIdx.x;
    if (b < 6144) {
        int u = b * 256 + threadIdx.x;
        if (u < 524288)       cast4(x,  x_bf,  u);
        else if (u < 786432)  cast4(Wq, wq_bf, u - 524288);
        else if (u < 1048576) cast4(Wk, wk_bf, u - 786432);
        else if (u < 1310720) cast4(Wv, wv_bf, u - 1048576);
        else                  cast4(Wp, wp_bf, u - 1310720);
    } else if (b < 6400) {
        int i = (b - 6144) * 256 + threadIdx.x;   // < 2048*32
        int t = i >> 5, j = i & 31;
        float inv = powf(10000.0f, -(float)j * (1.0f / 32.0f));
        float fr = (float)t * inv;
        cosT[i] = cosf(fr);
        sinT[i] = sinf(fr);
    } else if (threadIdx.x == 0) {
        float s1 = 0.f, s2 = 0.f;
        for (int i = 0; i < 32; ++i) { s1 += lq1[i] * lk1[i]; s2 += lq2[i] * lk2[i]; }
        *lam = expf(s1) - expf(s2) + 0.35550906759096928f;
    }
}

// ---------------- GEMM main loop: acc = A[M,K] * B[N,K]^T (64x128 tile) -------
__device__ __forceinline__ void gemm_main64(const u16* __restrict__ A,
                                            const u16* __restrict__ B,
                                            int m0, int n0, int K,
                                            u16* lA, u16* lB, f32x4 acc[2][4]) {
    const int tid = threadIdx.x;
    const int lane = tid & 63;
    const int wid = tid >> 6;
    const int wr = (wid >> 1) * 32;
    const int wc = (wid & 1) * 64;
    const int fr = lane & 15;
    const int kc = lane >> 4;
    const char* Ab = (const char*)A;
    const char* Bb = (const char*)B;
    const int rowbytes = K * 2;

    for (int k0 = 0; k0 < K; k0 += 32) {
        {
            int c = tid;
            gload16(Ab + (size_t)(m0 + (c >> 2)) * rowbytes + k0 * 2 + (c & 3) * 16,
                    (char*)lA + c * 16);
        }
#pragma unroll
        for (int i = 0; i < 2; ++i) {
            int c = i * 256 + tid;
            gload16(Bb + (size_t)(n0 + (c >> 2)) * rowbytes + k0 * 2 + (c & 3) * 16,
                    (char*)lB + c * 16);
        }
        __syncthreads();
        bf16x8 a[2], b[4];
#pragma unroll
        for (int m = 0; m < 2; ++m) a[m] = *(const bf16x8*)&lA[(wr + m * 16 + fr) * 32 + kc * 8];
#pragma unroll
        for (int n = 0; n < 4; ++n) b[n] = *(const bf16x8*)&lB[(wc + n * 16 + fr) * 32 + kc * 8];
#pragma unroll
        for (int m = 0; m < 2; ++m)
#pragma unroll
            for (int n = 0; n < 4; ++n)
                acc[m][n] = __builtin_amdgcn_mfma_f32_16x16x32_bf16(a[m], b[n], acc[m][n], 0, 0, 0);
        __syncthreads();
    }
}

// fused QKV GEMM: grid (24, 32); x-tiles 0-7 -> Q, 8-15 -> K, 16-23 -> V.
__global__ __launch_bounds__(256) void gemm_qkv(const u16* __restrict__ A,
                                                const u16* __restrict__ wq,
                                                const u16* __restrict__ wk,
                                                const u16* __restrict__ wv,
                                                const float* __restrict__ cosT,
                                                const float* __restrict__ sinT,
                                                u16* __restrict__ q_bf,
                                                u16* __restrict__ k_bf,
                                                u16* __restrict__ Vbf) {
    __shared__ __align__(16) u16 lA[64 * 32];
    __shared__ __align__(16) u16 lB[128 * 32];
    const int nt = blockIdx.x;
    const int which = nt >> 3;
    const u16* B = (which == 0) ? wq : (which == 1) ? wk : wv;
    const int m0 = blockIdx.y * 64;
    const int n0 = (nt & 7) * 128;

    f32x4 acc[2][4] = {};
    gemm_main64(A, B, m0, n0, 1024, lA, lB, acc);

    const int lane = threadIdx.x & 63;
    const int wid = threadIdx.x >> 6;
    const int wr = (wid >> 1) * 32;
    const int wc = (wid & 1) * 64;
    const int fr = lane & 15;
    const int rr = (lane >> 4) * 4;

    if (which == 2) {
#pragma unroll
        for (int m = 0; m < 2; ++m)
#pragma unroll
            for (int n = 0; n < 4; ++n)
#pragma unroll
                for (int r = 0; r < 4; ++r)
                    Vbf[(size_t)(m0 + wr + m * 16 + rr + r) * 1024 + n0 + wc + n * 16 + fr] =
                        f2bf(acc[m][n][r]);
        return;
    }

    const int cb = n0 + wc;
    const int plane = ((cb >> 9) << 3) | ((cb >> 6) & 7);
    u16* dstp = ((which == 0) ? q_bf : k_bf) + (size_t)plane * T_SEQ * 64;
#pragma unroll
    for (int m = 0; m < 2; ++m)
#pragma unroll
        for (int r = 0; r < 4; ++r) {
            int t = m0 + wr + m * 16 + rr + r;
            float s2 = 0.f;
#pragma unroll
            for (int n = 0; n < 4; ++n) { float a = acc[m][n][r]; s2 += a * a; }
            s2 += __shfl_xor(s2, 1); s2 += __shfl_xor(s2, 2);
            s2 += __shfl_xor(s2, 4); s2 += __shfl_xor(s2, 8);
            float inv = rsqrtf(s2 * (1.0f / 64.0f) + 1.1920929e-7f);
#pragma unroll
            for (int n = 0; n < 4; ++n) {
                float a = acc[m][n][r] * inv;
                float p_ = acc[m][n ^ 2][r] * inv;
                int jj = ((n & 1) << 4) + fr;
                float c = cosT[t * 32 + jj], sn = sinT[t * 32 + jj];
                float ov = (n < 2) ? (a * c + p_ * sn) : (a * c - p_ * sn);
                dstp[(size_t)t * 64 + n * 16 + fr] = f2bf(ov);
            }
        }
}

// grid (8, 32): 64x128 tiles
__global__ __launch_bounds__(256) void gemm_proj(const u16* __restrict__ A,
                                                 const u16* __restrict__ B,
                                                 float* __restrict__ C) {
    __shared__ __align__(16) u16 lA[64 * 32];
    __shared__ __align__(16) u16 lB[128 * 32];
    const int m0 = blockIdx.y * 64;
    const int n0 = blockIdx.x * 128;
    f32x4 acc[2][4] = {};
    gemm_main64(A, B, m0, n0, 1024, lA, lB, acc);
    const int lane = threadIdx.x & 63;
    const int wid = threadIdx.x >> 6;
    const int wr = (wid >> 1) * 32;
    const int wc = (wid & 1) * 64;
    const int fr = lane & 15;
    const int rr = (lane >> 4) * 4;
#pragma unroll
    for (int m = 0; m < 2; ++m)
#pragma unroll
        for (int n = 0; n < 4; ++n)
#pragma unroll
            for (int r = 0; r < 4; ++r)
                C[(size_t)(m0 + wr + m * 16 + rr + r) * 1024 + (n0 + wc + n * 16 + fr)] =
                    acc[m][n][r];
}

// ---------------- V transpose (bf16): Vbf[t][1024] -> vT[h*128+d][t] ----------
__global__ __launch_bounds__(256) void vtrans(const u16* __restrict__ Vbf,
                                              u16* __restrict__ vT) {
    __shared__ u16 tile[32][34];
    int tx = threadIdx.x & 31;
    int ty = threadIdx.x >> 5;
    int c0 = blockIdx.x * 32;
    int r0 = blockIdx.y * 32;
#pragma unroll
    for (int i = ty; i < 32; i += 8)
        tile[i][tx] = Vbf[(size_t)(r0 + i) * 1024 + c0 + tx];
    __syncthreads();
#pragma unroll
    for (int i = ty; i < 32; i += 8)
        vT[(size_t)(c0 + i) * T_SEQ + r0 + tx] = tile[tx][i];
}

// ---------------- flash attention, KV-chunked (QBLK=128, KV tile 64) ---------
// 640 blocks x 512 threads. Each block: one (plane, qt, chunk) unit, <=8 KV
// tiles. Writes per-chunk normalized O (fp16) + (m,l). Swapped QK^T and
// swapped PV: q-row = lane fr everywhere. 2-buf staging, counted vmcnt.
__global__ __launch_bounds__(512) void attn_kernel(const u16* __restrict__ q_bf,
                                                   const u16* __restrict__ k_bf,
                                                   const u16* __restrict__ vT_bf,
                                                   u16* __restrict__ Oc,
                                                   float2* __restrict__ ml) {
    __shared__ __align__(16) u16 lK[2][64 * 64];
    __shared__ __align__(16) u16 lV[2][128 * 64];
    __shared__ __align__(16) u16 lP[8][16 * 64];

    const int tid = threadIdx.x, lane = tid & 63, wid = tid >> 6;
    const int bid = blockIdx.x;
    const int plane = bid & 15;
    const int u = bid >> 4;             // 0..39, ordered qt descending
    int qt, chunk;
    if (u < 16)      { qt = 15 - (u >> 2);            chunk = u & 3; }
    else if (u < 28) { int w = u - 16; qt = 11 - w / 3; chunk = w % 3; }
    else if (u < 36) { int w = u - 28; qt = 7 - (w >> 1); chunk = w & 1; }
    else             { qt = 3 - (u - 36);             chunk = 0; }
    const int ntot = 2 * qt + 2;
    const int tb = chunk * 8;
    const int te = min(tb + 8, ntot);
    const int q0 = qt * 128;
    const int h = plane & 7;

    const u16* qp = q_bf + (size_t)plane * T_SEQ * 64;
    const char* kp = (const char*)(k_bf + (size_t)plane * T_SEQ * 64);
    const char* vp = (const char*)(vT_bf + (size_t)h * 128 * T_SEQ);
    const int fr = lane & 15, kc = lane >> 4;
    const int wsub = wid * 16;
    char* lPw = (char*)lP[wid];

    bf16x8 aq[2];
#pragma unroll
    for (int kq = 0; kq < 2; ++kq)
        aq[kq] = *(const bf16x8*)(qp + (size_t)(q0 + wsub + fr) * 64 + kq * 32 + kc * 8);

    f32x4 o[8] = {};                    // O^T: o[n8][r] = O[q=fr][d=n8*16+kc*4+r]
    float mi_l = -1e30f, li_l = 0.f;
    const float SL = 0.125f * 1.4426950408889634f;
    const int qrow = q0 + wsub + fr;

    auto stage = [&](int b, int t) {
        int s0 = t << 6;
        {
            int row = tid >> 3, cp = (tid & 7) * 16;
            gload16(kp + (size_t)(s0 + row) * 128 + swz(row, cp), (char*)lK[b] + tid * 16);
        }
#pragma unroll
        for (int i = 0; i < 2; ++i) {
            int c = i * 512 + tid;
            int row = c >> 3, cp = (c & 7) * 16;
            gload16(vp + (size_t)row * (T_SEQ * 2) + (size_t)s0 * 2 + swz(row, cp),
                    (char*)lV[b] + c * 16);
        }
    };

    auto compute = [&](const char* lKb, const char* lVb, int s0, bool diag) {
        f32x4 sacc[4] = {};
        __builtin_amdgcn_s_setprio(1);
#pragma unroll
        for (int kq = 0; kq < 2; ++kq)
#pragma unroll
            for (int n = 0; n < 4; ++n) {
                int row = n * 16 + fr;
                bf16x8 bk = *(const bf16x8*)(lKb + row * 128 + swz(row, kq * 64 + kc * 16));
                sacc[n] = __builtin_amdgcn_mfma_f32_16x16x32_bf16(bk, aq[kq], sacc[n], 0, 0, 0);
            }
        __builtin_amdgcn_s_setprio(0);

#pragma unroll
        for (int n = 0; n < 4; ++n)
#pragma unroll
            for (int r = 0; r < 4; ++r)
                sacc[n][r] *= SL;
        if (diag) {
#pragma unroll
            for (int n = 0; n < 4; ++n)
#pragma unroll
                for (int r = 0; r < 4; ++r)
                    if (s0 + n * 16 + kc * 4 + r > qrow) sacc[n][r] = -1e30f;
        }
        float rmax = -1e30f;
#pragma unroll
        for (int n = 0; n < 4; ++n)
#pragma unroll
            for (int r = 0; r < 4; ++r)
                rmax = fmaxf(rmax, sacc[n][r]);
        rmax = fmaxf(rmax, __shfl_xor(rmax, 16));
        rmax = fmaxf(rmax, __shfl_xor(rmax, 32));

        bool raise = rmax > mi_l + 8.0f;
        float f = raise ? __builtin_exp2f(mi_l - rmax) : 1.0f;
        if (raise) mi_l = rmax;

        float rs = 0.f;
#pragma unroll
        for (int n = 0; n < 4; ++n)
#pragma unroll
            for (int r = 0; r < 4; ++r) {
                float p = __builtin_exp2f(sacc[n][r] - mi_l);
                sacc[n][r] = p;
                rs += p;
            }
        rs += __shfl_xor(rs, 16);
        rs += __shfl_xor(rs, 32);
        li_l = li_l * f + rs;

        if (__any(raise)) {
#pragma unroll
            for (int n8 = 0; n8 < 8; ++n8)
#pragma unroll
                for (int r = 0; r < 4; ++r) o[n8][r] *= f;
        }

#pragma unroll
        for (int n = 0; n < 4; ++n) {
            ushort4 pk;
            pk.x = f2bf(sacc[n][0]); pk.y = f2bf(sacc[n][1]);
            pk.z = f2bf(sacc[n][2]); pk.w = f2bf(sacc[n][3]);
            *(ushort4*)(lPw + fr * 128 + ((n * 32 + kc * 8) ^ ((fr & 7) << 4))) = pk;
        }

        __builtin_amdgcn_s_setprio(1);
#pragma unroll
        for (int kk = 0; kk < 2; ++kk) {
            bf16x8 ap = *(const bf16x8*)(lPw + fr * 128 + swz(fr, kk * 64 + kc * 16));
#pragma unroll
            for (int n8 = 0; n8 < 8; ++n8) {
                int row = n8 * 16 + fr;
                bf16x8 bv = *(const bf16x8*)(lVb + row * 128 + swz(row, kk * 64 + kc * 16));
                o[n8] = __builtin_amdgcn_mfma_f32_16x16x32_bf16(bv, ap, o[n8], 0, 0, 0);
            }
        }
        __builtin_amdgcn_s_setprio(0);
    };

    stage(0, tb);
    for (int t = tb; t < te; ++t) {
        int ib = (t - tb) & 1;
        if (t + 1 < te) {
            stage(ib ^ 1, t + 1);
            asm volatile("s_waitcnt vmcnt(3)" ::: "memory");
        } else {
            asm volatile("s_waitcnt vmcnt(0)" ::: "memory");
        }
        __builtin_amdgcn_sched_barrier(0);
        __builtin_amdgcn_s_barrier();
        __builtin_amdgcn_sched_barrier(0);
        compute((const char*)lK[ib], (const char*)lV[ib], t << 6, t >= ntot - 2);
        __builtin_amdgcn_s_barrier();
    }

    // epilogue: normalized O (fp16) + (m,l)
    const float inv_l = 1.0f / li_l;
    u16* Ob = Oc + ((size_t)(plane * 4 + chunk) * T_SEQ + qrow) * 128;
#pragma unroll
    for (int n8 = 0; n8 < 8; ++n8) {
        ushort4 w;
        w.x = f2h(o[n8][0] * inv_l);
        w.y = f2h(o[n8][1] * inv_l);
        w.z = f2h(o[n8][2] * inv_l);
        w.w = f2h(o[n8][3] * inv_l);
        *(ushort4*)(Ob + n8 * 16 + kc * 4) = w;
    }
    if (kc == 0)
        ml[(size_t)(plane * 4 + chunk) * T_SEQ + qrow] = make_float2(mi_l, li_l);
}

// ---------------- merge chunks + diff (y1 - lambda*y2) -> bf16 ----------------
__global__ __launch_bounds__(256) void merge_kernel(const u16* __restrict__ Oc,
                                                    const float2* __restrict__ ml,
                                                    const float* __restrict__ lamp,
                                                    u16* __restrict__ yc) {
    int uu = blockIdx.x * 256 + threadIdx.x;   // < 524288
    int t = uu >> 8, rem = uu & 255, h = rem >> 5, d4 = (rem & 31) * 4;
    int qt = t >> 7;
    int nc = (qt + 4) >> 2;                    // ceil((qt+1)/4)
    float lamv = *lamp;
    float yv[2][4];
#pragma unroll
    for (int v = 0; v < 2; ++v) {
        int plane = v * 8 + h;
        float2 m_l[4];
        float M = -1e30f;
#pragma unroll
        for (int c = 0; c < 4; ++c)
            if (c < nc) {
                m_l[c] = ml[(size_t)(plane * 4 + c) * T_SEQ + t];
                M = fmaxf(M, m_l[c].x);
            }
        float den = 0.f, a0 = 0.f, a1 = 0.f, a2 = 0.f, a3 = 0.f;
#pragma unroll
        for (int c = 0; c < 4; ++c)
            if (c < nc) {
                float w = __builtin_exp2f(m_l[c].x - M) * m_l[c].y;
                den += w;
                ushort4 ov = *(const ushort4*)(Oc +
                    ((size_t)(plane * 4 + c) * T_SEQ + t) * 128 + d4);
                a0 += w * h2f(ov.x);
                a1 += w * h2f(ov.y);
                a2 += w * h2f(ov.z);
                a3 += w * h2f(ov.w);
            }
        float inv = 1.0f / den;
        yv[v][0] = a0 * inv; yv[v][1] = a1 * inv;
        yv[v][2] = a2 * inv; yv[v][3] = a3 * inv;
    }
    ushort4 o;
    o.x = f2bf(yv[0][0] - lamv * yv[1][0]);
    o.y = f2bf(yv[0][1] - lamv * yv[1][1]);
    o.z = f2bf(yv[0][2] - lamv * yv[1][2]);
    o.w = f2bf(yv[0][3] - lamv * yv[1][3]);
    *(ushort4*)(yc + (size_t)t * 1024 + h * 128 + d4) = o;
}

extern "C" void kernel_launch(void* const* d_in, const int* in_sizes, int n_in,
                              void* d_out, int out_size, void* d_ws, size_t ws_size,
                              hipStream_t stream) {
    const float* x   = (const float*)d_in[0];
    const float* Wq  = (const float*)d_in[1];
    const float* Wk  = (const float*)d_in[2];
    const float* Wv  = (const float*)d_in[3];
    const float* Wp  = (const float*)d_in[4];
    const float* lq1 = (const float*)d_in[5];
    const float* lk1 = (const float*)d_in[6];
    const float* lq2 = (const float*)d_in[7];
    const float* lk2 = (const float*)d_in[8];
    float* out = (float*)d_out;

    char* ws = (char*)d_ws;
    u16*    x_bf  = (u16*)(ws);                        //  4 MB
    u16*    wq_bf = (u16*)(ws + (4ull << 20));
    u16*    wk_bf = (u16*)(ws + (6ull << 20));
    u16*    wv_bf = (u16*)(ws + (8ull << 20));
    u16*    wp_bf = (u16*)(ws + (10ull << 20));
    u16*    Vbf   = (u16*)(ws + (12ull << 20));        //  4 MB
    u16*    q_bf  = (u16*)(ws + (16ull << 20));        //  4 MB
    u16*    k_bf  = (u16*)(ws + (20ull << 20));        //  4 MB
    u16*    vT_bf = (u16*)(ws + (24ull << 20));        //  4 MB
    u16*    Oc    = (u16*)(ws + (28ull << 20));        // 32 MB (fp16)
    float2* ml    = (float2*)(ws + (60ull << 20));     //  1 MB
    u16*    yc_bf = (u16*)(ws + (61ull << 20));        //  4 MB
    float*  cosT  = (float*)(ws + (65ull << 20));
    float*  sinT  = (float*)(ws + (65ull << 20) + (256ull << 10));
    float*  lam   = (float*)(ws + (65ull << 20) + (512ull << 10));

    prep<<<6401, 256, 0, stream>>>(x, Wq, Wk, Wv, Wp,
                                   x_bf, wq_bf, wk_bf, wv_bf, wp_bf,
                                   cosT, sinT, lq1, lk1, lq2, lk2, lam);

    gemm_qkv<<<dim3(24, 32), 256, 0, stream>>>(x_bf, wq_bf, wk_bf, wv_bf,
                                               cosT, sinT, q_bf, k_bf, Vbf);

    vtrans<<<dim3(32, 64), 256, 0, stream>>>(Vbf, vT_bf);

    attn_kernel<<<640, 512, 0, stream>>>(q_bf, k_bf, vT_bf, Oc, ml);

    merge_kernel<<<2048, 256, 0, stream>>>(Oc, ml, lam, yc_bf);

    gemm_proj<<<dim3(8, 32), 256, 0, stream>>>(yc_bf, wp_bf, out);
}

// Round 8
// 110.774 us; speedup vs baseline: 2.7427x; 1.0121x over previous
//
#include <hip/hip_runtime.h>
#include <hip/hip_bf16.h>

typedef __attribute__((ext_vector_type(4))) float f32x4;
typedef __attribute__((ext_vector_type(8))) short bf16x8;
typedef unsigned short u16;
typedef unsigned int u32;

#define T_SEQ 2048
#define DMODEL 1024

__device__ __forceinline__ u16 f2bf(float f) {
    __hip_bfloat16 h = __float2bfloat16(f);
    return __builtin_bit_cast(unsigned short, h);
}
__device__ __forceinline__ u16 f2h(float f) {
    _Float16 h = (_Float16)f;
    return __builtin_bit_cast(unsigned short, h);
}
__device__ __forceinline__ float h2f(u16 b) {
    return (float)__builtin_bit_cast(_Float16, b);
}

typedef const void __attribute__((address_space(1))) gvoid_t;
typedef void __attribute__((address_space(3))) lvoid_t;
__device__ __forceinline__ void gload16(const void* g, void* l) {
    __builtin_amdgcn_global_load_lds((gvoid_t*)g, (lvoid_t*)l, 16, 0, 0);
}

// XOR swizzle for 128B-row LDS tiles (kills 16-way ds_read_b128 conflicts)
__device__ __forceinline__ int swz(int row, int colb) {
    return colb ^ ((row & 7) << 4);
}

// ---------------- fused prep: casts + rope tables + lambda ----------------
__device__ __forceinline__ void cast4(const float* __restrict__ s,
                                      u16* __restrict__ d, int u) {
    int i = u * 4;
    float4 v = *(const float4*)(s + i);
    ushort4 o;
    o.x = f2bf(v.x); o.y = f2bf(v.y); o.z = f2bf(v.z); o.w = f2bf(v.w);
    *(ushort4*)(d + i) = o;
}

__global__ __launch_bounds__(256) void prep(const float* __restrict__ x,
                                            const float* __restrict__ Wq,
                                            const float* __restrict__ Wk,
                                            const float* __restrict__ Wv,
                                            const float* __restrict__ Wp,
                                            u16* __restrict__ x_bf, u16* __restrict__ wq_bf,
                                            u16* __restrict__ wk_bf, u16* __restrict__ wv_bf,
                                            u16* __restrict__ wp_bf,
                                            float* __restrict__ cosT, float* __restrict__ sinT,
                                            const float* __restrict__ lq1, const float* __restrict__ lk1,
                                            const float* __restrict__ lq2, const float* __restrict__ lk2,
                                            float* __restrict__ lam) {
    int b = blockIdx.x;
    if (b < 6144) {
        int u = b * 256 + threadIdx.x;
        if (u < 524288)       cast4(x,  x_bf,  u);
        else if (u < 786432)  cast4(Wq, wq_bf, u - 524288);
        else if (u < 1048576) cast4(Wk, wk_bf, u - 786432);
        else if (u < 1310720) cast4(Wv, wv_bf, u - 1048576);
        else                  cast4(Wp, wp_bf, u - 1310720);
    } else if (b < 6400) {
        int i = (b - 6144) * 256 + threadIdx.x;   // < 2048*32
        int t = i >> 5, j = i & 31;
        float inv = powf(10000.0f, -(float)j * (1.0f / 32.0f));
        float fr = (float)t * inv;
        cosT[i] = cosf(fr);
        sinT[i] = sinf(fr);
    } else if (threadIdx.x == 0) {
        float s1 = 0.f, s2 = 0.f;
        for (int i = 0; i < 32; ++i) { s1 += lq1[i] * lk1[i]; s2 += lq2[i] * lk2[i]; }
        *lam = expf(s1) - expf(s2) + 0.35550906759096928f;
    }
}

// ---------------- GEMM main loop: acc = A[M,K] * B[N,K]^T (64x128 tile) -------
__device__ __forceinline__ void gemm_main64(const u16* __restrict__ A,
                                            const u16* __restrict__ B,
                                            int m0, int n0, int K,
                                            u16* lA, u16* lB, f32x4 acc[2][4]) {
    const int tid = threadIdx.x;
    const int lane = tid & 63;
    const int wid = tid >> 6;
    const int wr = (wid >> 1) * 32;
    const int wc = (wid & 1) * 64;
    const int fr = lane & 15;
    const int kc = lane >> 4;
    const char* Ab = (const char*)A;
    const char* Bb = (const char*)B;
    const int rowbytes = K * 2;

    for (int k0 = 0; k0 < K; k0 += 32) {
        {
            int c = tid;
            gload16(Ab + (size_t)(m0 + (c >> 2)) * rowbytes + k0 * 2 + (c & 3) * 16,
                    (char*)lA + c * 16);
        }
#pragma unroll
        for (int i = 0; i < 2; ++i) {
            int c = i * 256 + tid;
            gload16(Bb + (size_t)(n0 + (c >> 2)) * rowbytes + k0 * 2 + (c & 3) * 16,
                    (char*)lB + c * 16);
        }
        __syncthreads();
        bf16x8 a[2], b[4];
#pragma unroll
        for (int m = 0; m < 2; ++m) a[m] = *(const bf16x8*)&lA[(wr + m * 16 + fr) * 32 + kc * 8];
#pragma unroll
        for (int n = 0; n < 4; ++n) b[n] = *(const bf16x8*)&lB[(wc + n * 16 + fr) * 32 + kc * 8];
#pragma unroll
        for (int m = 0; m < 2; ++m)
#pragma unroll
            for (int n = 0; n < 4; ++n)
                acc[m][n] = __builtin_amdgcn_mfma_f32_16x16x32_bf16(a[m], b[n], acc[m][n], 0, 0, 0);
        __syncthreads();
    }
}

// fused QKV GEMM: grid (24, 32); x-tiles 0-7 -> Q, 8-15 -> K, 16-23 -> V.
// Q epilogue additionally folds in attn scale * log2(e).
__global__ __launch_bounds__(256) void gemm_qkv(const u16* __restrict__ A,
                                                const u16* __restrict__ wq,
                                                const u16* __restrict__ wk,
                                                const u16* __restrict__ wv,
                                                const float* __restrict__ cosT,
                                                const float* __restrict__ sinT,
                                                u16* __restrict__ q_bf,
                                                u16* __restrict__ k_bf,
                                                u16* __restrict__ Vbf) {
    __shared__ __align__(16) u16 lA[64 * 32];
    __shared__ __align__(16) u16 lB[128 * 32];
    const int nt = blockIdx.x;
    const int which = nt >> 3;
    const u16* B = (which == 0) ? wq : (which == 1) ? wk : wv;
    const int m0 = blockIdx.y * 64;
    const int n0 = (nt & 7) * 128;

    f32x4 acc[2][4] = {};
    gemm_main64(A, B, m0, n0, 1024, lA, lB, acc);

    const int lane = threadIdx.x & 63;
    const int wid = threadIdx.x >> 6;
    const int wr = (wid >> 1) * 32;
    const int wc = (wid & 1) * 64;
    const int fr = lane & 15;
    const int rr = (lane >> 4) * 4;

    if (which == 2) {
#pragma unroll
        for (int m = 0; m < 2; ++m)
#pragma unroll
            for (int n = 0; n < 4; ++n)
#pragma unroll
                for (int r = 0; r < 4; ++r)
                    Vbf[(size_t)(m0 + wr + m * 16 + rr + r) * 1024 + n0 + wc + n * 16 + fr] =
                        f2bf(acc[m][n][r]);
        return;
    }

    const float oscale = (which == 0) ? 0.18033688011112042f : 1.0f;  // 0.125*log2(e)
    const int cb = n0 + wc;
    const int plane = ((cb >> 9) << 3) | ((cb >> 6) & 7);
    u16* dstp = ((which == 0) ? q_bf : k_bf) + (size_t)plane * T_SEQ * 64;
#pragma unroll
    for (int m = 0; m < 2; ++m)
#pragma unroll
        for (int r = 0; r < 4; ++r) {
            int t = m0 + wr + m * 16 + rr + r;
            float s2 = 0.f;
#pragma unroll
            for (int n = 0; n < 4; ++n) { float a = acc[m][n][r]; s2 += a * a; }
            s2 += __shfl_xor(s2, 1); s2 += __shfl_xor(s2, 2);
            s2 += __shfl_xor(s2, 4); s2 += __shfl_xor(s2, 8);
            float inv = rsqrtf(s2 * (1.0f / 64.0f) + 1.1920929e-7f);
#pragma unroll
            for (int n = 0; n < 4; ++n) {
                float a = acc[m][n][r] * inv;
                float p_ = acc[m][n ^ 2][r] * inv;
                int jj = ((n & 1) << 4) + fr;
                float c = cosT[t * 32 + jj], sn = sinT[t * 32 + jj];
                float ov = (n < 2) ? (a * c + p_ * sn) : (a * c - p_ * sn);
                dstp[(size_t)t * 64 + n * 16 + fr] = f2bf(ov * oscale);
            }
        }
}

// grid (8, 32): 64x128 tiles
__global__ __launch_bounds__(256) void gemm_proj(const u16* __restrict__ A,
                                                 const u16* __restrict__ B,
                                                 float* __restrict__ C) {
    __shared__ __align__(16) u16 lA[64 * 32];
    __shared__ __align__(16) u16 lB[128 * 32];
    const int m0 = blockIdx.y * 64;
    const int n0 = blockIdx.x * 128;
    f32x4 acc[2][4] = {};
    gemm_main64(A, B, m0, n0, 1024, lA, lB, acc);
    const int lane = threadIdx.x & 63;
    const int wid = threadIdx.x >> 6;
    const int wr = (wid >> 1) * 32;
    const int wc = (wid & 1) * 64;
    const int fr = lane & 15;
    const int rr = (lane >> 4) * 4;
#pragma unroll
    for (int m = 0; m < 2; ++m)
#pragma unroll
        for (int n = 0; n < 4; ++n)
#pragma unroll
            for (int r = 0; r < 4; ++r)
                C[(size_t)(m0 + wr + m * 16 + rr + r) * 1024 + (n0 + wc + n * 16 + fr)] =
                    acc[m][n][r];
}

// ---------------- V transpose (bf16): Vbf[t][1024] -> vT[h*128+d][t] ----------
__global__ __launch_bounds__(256) void vtrans(const u16* __restrict__ Vbf,
                                              u16* __restrict__ vT) {
    __shared__ u16 tile[32][34];
    int tx = threadIdx.x & 31;
    int ty = threadIdx.x >> 5;
    int c0 = blockIdx.x * 32;
    int r0 = blockIdx.y * 32;
#pragma unroll
    for (int i = ty; i < 32; i += 8)
        tile[i][tx] = Vbf[(size_t)(r0 + i) * 1024 + c0 + tx];
    __syncthreads();
#pragma unroll
    for (int i = ty; i < 32; i += 8)
        vT[(size_t)(c0 + i) * T_SEQ + r0 + tx] = tile[tx][i];
}

// ---------------- flash attention, KV-chunked (QBLK=128, KV tile 64) ---------
// 640 blocks x 512 threads, 3 blocks/CU (48KB LDS). Per-chunk normalized O
// (fp16) + (m,l). Swapped QK^T and swapped PV; P stays IN REGISTERS:
// cvt_pk_bf16 pack + ds_bpermute re-distribution builds the PV B-operand.
__global__ __launch_bounds__(512, 6) void attn_kernel(const u16* __restrict__ q_bf,
                                                      const u16* __restrict__ k_bf,
                                                      const u16* __restrict__ vT_bf,
                                                      u16* __restrict__ Oc,
                                                      float2* __restrict__ ml) {
    __shared__ __align__(16) u16 lK[2][64 * 64];
    __shared__ __align__(16) u16 lV[2][128 * 64];

    const int tid = threadIdx.x, lane = tid & 63, wid = tid >> 6;
    const int bid = blockIdx.x;
    const int plane = bid & 15;
    const int u = bid >> 4;             // 0..39, ordered qt descending
    int qt, chunk;
    if (u < 16)      { qt = 15 - (u >> 2);            chunk = u & 3; }
    else if (u < 28) { int w = u - 16; qt = 11 - w / 3; chunk = w % 3; }
    else if (u < 36) { int w = u - 28; qt = 7 - (w >> 1); chunk = w & 1; }
    else             { qt = 3 - (u - 36);             chunk = 0; }
    const int ntot = 2 * qt + 2;
    const int tb = chunk * 8;
    const int te = min(tb + 8, ntot);
    const int q0 = qt * 128;
    const int h = plane & 7;

    const u16* qp = q_bf + (size_t)plane * T_SEQ * 64;
    const char* kp = (const char*)(k_bf + (size_t)plane * T_SEQ * 64);
    const char* vp = (const char*)(vT_bf + (size_t)h * 128 * T_SEQ);
    const int fr = lane & 15, kc = lane >> 4;
    const int wsub = wid * 16;

    bf16x8 aq[2];
#pragma unroll
    for (int kq = 0; kq < 2; ++kq)
        aq[kq] = *(const bf16x8*)(qp + (size_t)(q0 + wsub + fr) * 64 + kq * 32 + kc * 8);

    f32x4 o[8] = {};                    // O^T: o[n8][r] = O[q=fr][d=n8*16+kc*4+r]
    float mi_l = -1e30f, li_l = 0.f;
    const int qrow = q0 + wsub + fr;
    const int srcA = fr + ((kc & 1) << 5);   // P-redistribution source lanes
    const int srcB = srcA + 16;
    const bool hi = kc >= 2;

    auto stage = [&](int b, int t) {
        int s0 = t << 6;
        {
            int row = tid >> 3, cp = (tid & 7) * 16;
            gload16(kp + (size_t)(s0 + row) * 128 + swz(row, cp), (char*)lK[b] + tid * 16);
        }
#pragma unroll
        for (int i = 0; i < 2; ++i) {
            int c = i * 512 + tid;
            int row = c >> 3, cp = (c & 7) * 16;
            gload16(vp + (size_t)row * (T_SEQ * 2) + (size_t)s0 * 2 + swz(row, cp),
                    (char*)lV[b] + c * 16);
        }
    };

    auto compute = [&](const char* lKb, const char* lVb, int s0, bool diag) {
        // S^T (pre-scaled: SL folded into Q): sacc[n][r] = S[q=fr][k=s0+n*16+kc*4+r]
        f32x4 sacc[4] = {};
        __builtin_amdgcn_s_setprio(1);
#pragma unroll
        for (int kq = 0; kq < 2; ++kq)
#pragma unroll
            for (int n = 0; n < 4; ++n) {
                int row = n * 16 + fr;
                bf16x8 bk = *(const bf16x8*)(lKb + row * 128 + swz(row, kq * 64 + kc * 16));
                sacc[n] = __builtin_amdgcn_mfma_f32_16x16x32_bf16(bk, aq[kq], sacc[n], 0, 0, 0);
            }
        __builtin_amdgcn_s_setprio(0);

        if (diag) {
#pragma unroll
            for (int n = 0; n < 4; ++n)
#pragma unroll
                for (int r = 0; r < 4; ++r)
                    if (s0 + n * 16 + kc * 4 + r > qrow) sacc[n][r] = -1e30f;
        }
        float rmax = -1e30f;
#pragma unroll
        for (int n = 0; n < 4; ++n)
#pragma unroll
            for (int r = 0; r < 4; ++r)
                rmax = fmaxf(rmax, sacc[n][r]);
        rmax = fmaxf(rmax, __shfl_xor(rmax, 16));
        rmax = fmaxf(rmax, __shfl_xor(rmax, 32));

        bool raise = rmax > mi_l + 8.0f;   // T13 defer-max (exp2 domain)
        float f = raise ? __builtin_exp2f(mi_l - rmax) : 1.0f;
        if (raise) mi_l = rmax;

        float rs = 0.f;
#pragma unroll
        for (int n = 0; n < 4; ++n)
#pragma unroll
            for (int r = 0; r < 4; ++r) {
                float p = __builtin_exp2f(sacc[n][r] - mi_l);
                sacc[n][r] = p;
                rs += p;
            }
        rs += __shfl_xor(rs, 16);
        rs += __shfl_xor(rs, 32);
        li_l = li_l * f + rs;

        if (__any(raise)) {
#pragma unroll
            for (int n8 = 0; n8 < 8; ++n8)
#pragma unroll
                for (int r = 0; r < 4; ++r) o[n8][r] *= f;
        }

        // pack P -> bf16 pairs: w32[n][w] = {P[k=n*16+kc*4+2w], [+1]}
        u32 w32[4][2];
#pragma unroll
        for (int n = 0; n < 4; ++n)
#pragma unroll
            for (int w = 0; w < 2; ++w) {
                u32 rpk;
                asm("v_cvt_pk_bf16_f32 %0, %1, %2"
                    : "=v"(rpk) : "v"(sacc[n][2 * w]), "v"(sacc[n][2 * w + 1]));
                w32[n][w] = rpk;
            }

        // PV: O^T += V^T x P. B-operand built in-register via bpermute.
        __builtin_amdgcn_s_setprio(1);
#pragma unroll
        for (int kk = 0; kk < 2; ++kk) {
            u32 a0 = (u32)__shfl((int)w32[2 * kk][0], srcA);
            u32 a1 = (u32)__shfl((int)w32[2 * kk][1], srcA);
            u32 a2 = (u32)__shfl((int)w32[2 * kk][0], srcB);
            u32 a3 = (u32)__shfl((int)w32[2 * kk][1], srcB);
            u32 b0 = (u32)__shfl((int)w32[2 * kk + 1][0], srcA);
            u32 b1 = (u32)__shfl((int)w32[2 * kk + 1][1], srcA);
            u32 b2 = (u32)__shfl((int)w32[2 * kk + 1][0], srcB);
            u32 b3 = (u32)__shfl((int)w32[2 * kk + 1][1], srcB);
            union { u32 u4[4]; bf16x8 v; } ap;
            ap.u4[0] = hi ? b0 : a0;
            ap.u4[1] = hi ? b1 : a1;
            ap.u4[2] = hi ? b2 : a2;
            ap.u4[3] = hi ? b3 : a3;
#pragma unroll
            for (int n8 = 0; n8 < 8; ++n8) {
                int row = n8 * 16 + fr;
                bf16x8 bv = *(const bf16x8*)(lVb + row * 128 + swz(row, kk * 64 + kc * 16));
                o[n8] = __builtin_amdgcn_mfma_f32_16x16x32_bf16(bv, ap.v, o[n8], 0, 0, 0);
            }
        }
        __builtin_amdgcn_s_setprio(0);
    };

    stage(0, tb);
    for (int t = tb; t < te; ++t) {
        int ib = (t - tb) & 1;
        if (t + 1 < te) {
            stage(ib ^ 1, t + 1);
            asm volatile("s_waitcnt vmcnt(3)" ::: "memory");
        } else {
            asm volatile("s_waitcnt vmcnt(0)" ::: "memory");
        }
        __builtin_amdgcn_sched_barrier(0);
        __builtin_amdgcn_s_barrier();
        __builtin_amdgcn_sched_barrier(0);
        compute((const char*)lK[ib], (const char*)lV[ib], t << 6, t >= ntot - 2);
        __builtin_amdgcn_s_barrier();
    }

    // epilogue: normalized O (fp16) + (m,l)
    const float inv_l = 1.0f / li_l;
    u16* Ob = Oc + ((size_t)(plane * 4 + chunk) * T_SEQ + qrow) * 128;
#pragma unroll
    for (int n8 = 0; n8 < 8; ++n8) {
        ushort4 w;
        w.x = f2h(o[n8][0] * inv_l);
        w.y = f2h(o[n8][1] * inv_l);
        w.z = f2h(o[n8][2] * inv_l);
        w.w = f2h(o[n8][3] * inv_l);
        *(ushort4*)(Ob + n8 * 16 + kc * 4) = w;
    }
    if (kc == 0)
        ml[(size_t)(plane * 4 + chunk) * T_SEQ + qrow] = make_float2(mi_l, li_l);
}

// ---------------- merge chunks + diff (y1 - lambda*y2) -> bf16 ----------------
__global__ __launch_bounds__(256) void merge_kernel(const u16* __restrict__ Oc,
                                                    const float2* __restrict__ ml,
                                                    const float* __restrict__ lamp,
                                                    u16* __restrict__ yc) {
    int uu = blockIdx.x * 256 + threadIdx.x;   // < 524288
    int t = uu >> 8, rem = uu & 255, h = rem >> 5, d4 = (rem & 31) * 4;
    int qt = t >> 7;
    int nc = (qt + 4) >> 2;                    // ceil((qt+1)/4)
    float lamv = *lamp;
    float yv[2][4];
#pragma unroll
    for (int v = 0; v < 2; ++v) {
        int plane = v * 8 + h;
        float2 m_l[4];
        float M = -1e30f;
#pragma unroll
        for (int c = 0; c < 4; ++c)
            if (c < nc) {
                m_l[c] = ml[(size_t)(plane * 4 + c) * T_SEQ + t];
                M = fmaxf(M, m_l[c].x);
            }
        float den = 0.f, a0 = 0.f, a1 = 0.f, a2 = 0.f, a3 = 0.f;
#pragma unroll
        for (int c = 0; c < 4; ++c)
            if (c < nc) {
                float w = __builtin_exp2f(m_l[c].x - M) * m_l[c].y;
                den += w;
                ushort4 ov = *(const ushort4*)(Oc +
                    ((size_t)(plane * 4 + c) * T_SEQ + t) * 128 + d4);
                a0 += w * h2f(ov.x);
                a1 += w * h2f(ov.y);
                a2 += w * h2f(ov.z);
                a3 += w * h2f(ov.w);
            }
        float inv = 1.0f / den;
        yv[v][0] = a0 * inv; yv[v][1] = a1 * inv;
        yv[v][2] = a2 * inv; yv[v][3] = a3 * inv;
    }
    ushort4 o;
    o.x = f2bf(yv[0][0] - lamv * yv[1][0]);
    o.y = f2bf(yv[0][1] - lamv * yv[1][1]);
    o.z = f2bf(yv[0][2] - lamv * yv[1][2]);
    o.w = f2bf(yv[0][3] - lamv * yv[1][3]);
    *(ushort4*)(yc + (size_t)t * 1024 + h * 128 + d4) = o;
}

extern "C" void kernel_launch(void* const* d_in, const int* in_sizes, int n_in,
                              void* d_out, int out_size, void* d_ws, size_t ws_size,
                              hipStream_t stream) {
    const float* x   = (const float*)d_in[0];
    const float* Wq  = (const float*)d_in[1];
    const float* Wk  = (const float*)d_in[2];
    const float* Wv  = (const float*)d_in[3];
    const float* Wp  = (const float*)d_in[4];
    const float* lq1 = (const float*)d_in[5];
    const float* lk1 = (const float*)d_in[6];
    const float* lq2 = (const float*)d_in[7];
    const float* lk2 = (const float*)d_in[8];
    float* out = (float*)d_out;

    char* ws = (char*)d_ws;
    u16*    x_bf  = (u16*)(ws);                        //  4 MB
    u16*    wq_bf = (u16*)(ws + (4ull << 20));
    u16*    wk_bf = (u16*)(ws + (6ull << 20));
    u16*    wv_bf = (u16*)(ws + (8ull << 20));
    u16*    wp_bf = (u16*)(ws + (10ull << 20));
    u16*    Vbf   = (u16*)(ws + (12ull << 20));        //  4 MB
    u16*    q_bf  = (u16*)(ws + (16ull << 20));        //  4 MB
    u16*    k_bf  = (u16*)(ws + (20ull << 20));        //  4 MB
    u16*    vT_bf = (u16*)(ws + (24ull << 20));        //  4 MB
    u16*    Oc    = (u16*)(ws + (28ull << 20));        // 32 MB (fp16)
    float2* ml    = (float2*)(ws + (60ull << 20));     //  1 MB
    u16*    yc_bf = (u16*)(ws + (61ull << 20));        //  4 MB
    float*  cosT  = (float*)(ws + (65ull << 20));
    float*  sinT  = (float*)(ws + (65ull << 20) + (256ull << 10));
    float*  lam   = (float*)(ws + (65ull << 20) + (512ull << 10));

    prep<<<6401, 256, 0, stream>>>(x, Wq, Wk, Wv, Wp,
                                   x_bf, wq_bf, wk_bf, wv_bf, wp_bf,
                                   cosT, sinT, lq1, lk1, lq2, lk2, lam);

    gemm_qkv<<<dim3(24, 32), 256, 0, stream>>>(x_bf, wq_bf, wk_bf, wv_bf,
                                               cosT, sinT, q_bf, k_bf, Vbf);

    vtrans<<<dim3(32, 64), 256, 0, stream>>>(Vbf, vT_bf);

    attn_kernel<<<640, 512, 0, stream>>>(q_bf, k_bf, vT_bf, Oc, ml);

    merge_kernel<<<2048, 256, 0, stream>>>(Oc, ml, lam, yc_bf);

    gemm_proj<<<dim3(8, 32), 256, 0, stream>>>(yc_bf, wp_bf, out);
}